// Round 8
// baseline (312.732 us; speedup 1.0000x reference)
//
#include <hip/hip_runtime.h>
#include <hip/hip_bf16.h>

typedef __bf16 bf16x8 __attribute__((ext_vector_type(8)));
typedef float f32x4 __attribute__((ext_vector_type(4)));
typedef unsigned short ushort8 __attribute__((ext_vector_type(8)));

#define DEVINL static __device__ __forceinline__

DEVINL unsigned f2bf(float f){
  unsigned u = __float_as_uint(f);
  return (u + 0x7fffu + ((u >> 16) & 1u)) >> 16;
}

DEVINL f32x4 MFMA(bf16x8 a, bf16x8 b, f32x4 c){
  return __builtin_amdgcn_mfma_f32_16x16x32_bf16(a, b, c, 0, 0, 0);
}

typedef const __attribute__((address_space(1))) unsigned int* gas_t;
typedef __attribute__((address_space(3))) unsigned int* las_t;
DEVINL void gload_lds16(const void* g, void* l){
  __builtin_amdgcn_global_load_lds((gas_t)g, (las_t)l, 16, 0, 0);
}

// T12 primitives. Verified semantics (gfx950 ISA):
//   sw32(a,b): a=[a.row0, b.row0], b=[a.row1, b.row1]   (row = 32 lanes)
//   sw16(a,b): a=[a.g0, b.g0, a.g2, b.g2], b=[a.g1, b.g1, a.g3, b.g3]  (g = 16 lanes)
DEVINL unsigned cvtpk(float lo, float hi){
  unsigned r; asm("v_cvt_pk_bf16_f32 %0, %1, %2" : "=v"(r) : "v"(lo), "v"(hi)); return r;
}
DEVINL void sw32(unsigned &a, unsigned &b){ asm("v_permlane32_swap_b32 %0, %1" : "+v"(a), "+v"(b)); }
DEVINL void sw16(unsigned &a, unsigned &b){ asm("v_permlane16_swap_b32 %0, %1" : "+v"(a), "+v"(b)); }

// ---------- fp32 -> bf16 pack (n multiple of 4) ----------
__global__ void k_cvt(const float* __restrict__ s, unsigned short* __restrict__ d, int n){
  int i = (blockIdx.x * blockDim.x + threadIdx.x) * 4;
  if (i >= n) return;
  float4 v = *(const float4*)(s + i);
  ushort4 o;
  o.x = (unsigned short)f2bf(v.x); o.y = (unsigned short)f2bf(v.y);
  o.z = (unsigned short)f2bf(v.z); o.w = (unsigned short)f2bf(v.w);
  *(ushort4*)(d + i) = o;
}

// ---------- fused transposes; WQ additionally pre-scaled by SC*log2(e) ----------
__global__ void k_tr4(const float* __restrict__ WQ, const float* __restrict__ WK,
                      const float* __restrict__ WV, const float* __restrict__ Wout,
                      unsigned short* __restrict__ wT, unsigned short* __restrict__ woT){
  __shared__ float t[32][33];
  int id = blockIdx.x;
  const float* s; unsigned short* d; int R, C, tile;
  float scl = 1.0f;
  if (id < 1536){
    int z = id >> 9; tile = id & 511;
    s = (z == 0) ? WQ : ((z == 1) ? WK : WV);
    if (z == 0) scl = 0.25503510f;   // (1/sqrt(32)) * log2(e) folded into WQ
    d = wT + z * 524288; R = 256; C = 2048;
  } else {
    tile = id - 1536; s = Wout; d = woT; R = 2048; C = 256;
  }
  int tilesX = C >> 5;
  int c0 = (tile % tilesX) * 32, r0 = (tile / tilesX) * 32;
  int tx = threadIdx.x, ty = threadIdx.y;
  #pragma unroll
  for (int k2 = 0; k2 < 4; k2++) t[ty + 8*k2][tx] = s[(r0 + ty + 8*k2) * C + c0 + tx];
  __syncthreads();
  #pragma unroll
  for (int k2 = 0; k2 < 4; k2++) d[(c0 + ty + 8*k2) * R + r0 + tx] = (unsigned short)f2bf(t[tx][ty + 8*k2] * scl);
}

// ---------- QKV projection -> q [8192,2048], K packed-frag layout, val -> vT[b,h,c,s] ----------
// Packed K: kp[(b*8+h)<<20 bytes], per 32-t tile: 16 frags (tf*8+kf) x 64 lanes x 16B.
// Element (s,c): t0=s>>5,trow=s&31,tf=trow>>4,lr=trow&15; kf=c>>5,lg=(c>>3)&3,e=c&7
//   byte = head + t0*16384 + (tf*8+kf)*1024 + (lg*16+lr)*16 + e*2
__global__ __launch_bounds__(256, 2) void k_qkv(const unsigned short* __restrict__ vb,
    const unsigned short* __restrict__ wT,
    unsigned short* __restrict__ qo, char* __restrict__ kpB, unsigned short* __restrict__ vTo){
  __shared__ unsigned short As[128 * 72];
  __shared__ unsigned short Bs[128 * 72];
  int tid = threadIdx.x;
  int lane = tid & 63, wid = tid >> 6;
  int lr = lane & 15, lg = lane >> 4;
  int wm = (wid >> 1) * 64, wn = (wid & 1) * 64;
  int bn = blockIdx.x, bm = blockIdx.y, z = blockIdx.z;

  const unsigned short* Ag = vb + (bm * 128) * 256;
  const unsigned short* Bg = wT + z * (2048 * 256) + (bn * 128) * 256;

  f32x4 acc[4][4] = {};
  for (int kt = 0; kt < 4; kt++){
    ushort8 ra[4], rb[4];
    #pragma unroll
    for (int p = 0; p < 4; p++){
      int idx = p * 256 + tid; int row = idx >> 3, ch = idx & 7;
      ra[p] = *(const ushort8*)(Ag + row * 256 + kt * 64 + ch * 8);
      rb[p] = *(const ushort8*)(Bg + row * 256 + kt * 64 + ch * 8);
    }
    __syncthreads();
    #pragma unroll
    for (int p = 0; p < 4; p++){
      int idx = p * 256 + tid; int row = idx >> 3, ch = idx & 7;
      *(ushort8*)(As + row * 72 + ch * 8) = ra[p];
      *(ushort8*)(Bs + row * 72 + ch * 8) = rb[p];
    }
    __syncthreads();
    #pragma unroll
    for (int kf = 0; kf < 2; kf++){
      bf16x8 af[4], bfr[4];
      #pragma unroll
      for (int mf = 0; mf < 4; mf++) af[mf]  = *(const bf16x8*)(As + (wm + mf*16 + lr) * 72 + kf*32 + lg*8);
      #pragma unroll
      for (int nf = 0; nf < 4; nf++) bfr[nf] = *(const bf16x8*)(Bs + (wn + nf*16 + lr) * 72 + kf*32 + lg*8);
      #pragma unroll
      for (int mf = 0; mf < 4; mf++)
        #pragma unroll
        for (int nf = 0; nf < 4; nf++)
          acc[mf][nf] = MFMA(af[mf], bfr[nf], acc[mf][nf]);
    }
  }
  if (z == 0){
    #pragma unroll
    for (int mf = 0; mf < 4; mf++)
      #pragma unroll
      for (int nf = 0; nf < 4; nf++){
        int mg = bm*128 + wm + mf*16 + lg*4;
        int ng = bn*128 + wn + nf*16 + lr;
        #pragma unroll
        for (int r2 = 0; r2 < 4; r2++) qo[(mg + r2) * 2048 + ng] = (unsigned short)f2bf(acc[mf][nf][r2]);
      }
  } else if (z == 1){
    #pragma unroll
    for (int mf = 0; mf < 4; mf++)
      #pragma unroll
      for (int nf = 0; nf < 4; nf++){
        int mg = bm*128 + wm + mf*16 + lg*4;
        int ng = bn*128 + wn + nf*16 + lr;
        int bb = mg >> 11, si = mg & 2047;
        int hh = ng >> 8, cc = ng & 255;
        int t0 = si >> 5, trow = si & 31, tf = trow >> 4, lrr = trow & 15;
        int kfi = cc >> 5, lgg = (cc >> 3) & 3, e = cc & 7;
        size_t base = ((size_t)(bb*8 + hh) << 20) + t0*16384 + (tf*8 + kfi)*1024 + (lgg*16 + lrr)*16 + e*2;
        #pragma unroll
        for (int r2 = 0; r2 < 4; r2++)
          *(unsigned short*)(kpB + base + r2*16) = (unsigned short)f2bf(acc[mf][nf][r2]);
      }
  } else {
    #pragma unroll
    for (int mf = 0; mf < 4; mf++)
      #pragma unroll
      for (int nf = 0; nf < 4; nf++){
        int mg = bm*128 + wm + mf*16 + lg*4;
        int ng = bn*128 + wn + nf*16 + lr;
        int bb = mg >> 11, s = mg & 2047, hh = ng >> 8, cc = ng & 255;
        uint2 w;
        w.x = f2bf(acc[mf][nf][0]) | (f2bf(acc[mf][nf][1]) << 16);
        w.y = f2bf(acc[mf][nf][2]) | (f2bf(acc[mf][nf][3]) << 16);
        *(uint2*)(vTo + (size_t)((bb*8 + hh) * 256 + cc) * 2048 + s) = w;
      }
  }
}

// ---------- flash attention: 4 waves/block; K direct-from-global (packed frags, L1/L2);
// V LDS-staged (dbuf 32KB); P in registers (permlane butterfly); exp2 with no fma/shift ----------
__global__ __launch_bounds__(256, 2) void k_attn(const unsigned short* __restrict__ q,
    const char* __restrict__ kp, const unsigned short* __restrict__ vT,
    unsigned short* __restrict__ u){
  __shared__ unsigned short Vs[2][8192];
  int tid = threadIdx.x;
  int lane = tid & 63, wid = tid >> 6;
  int lr = lane & 15, lg = lane >> 4;
  // XCD-chunked swizzle: 512 blocks = 8 XCD x 64; each XCD gets 4 contiguous (b,h) pairs
  int g = (blockIdx.x & 7) * 64 + (blockIdx.x >> 3);
  int bh = g >> 4, qt = g & 15;
  int b = bh >> 3, h = bh & 7;
  int q0 = qt * 128;

  const char* kph = kp + ((size_t)(b * 8 + h) << 20);
  const char* vgB = (const char*)(vT + (size_t)(b * 8 + h) * 256 * 2048);
  const unsigned short* qg = q + (size_t)(b * 2048 + q0 + wid * 32) * 2048 + h * 256;

  // V staging: 16 chunks of 1KB per 32-t tile; 4 issues per wave
  const char* sp[4];
  #pragma unroll
  for (int j = 0; j < 4; j++){
    int c2 = wid * 256 + j * 64 + lane;
    int blk = c2 >> 5, ts = (c2 >> 3) & 3, low3 = c2 & 7;
    int crow = blk * 8 + (low3 ^ (ts * 2));
    sp[j] = vgB + (size_t)crow * 4096 + ts * 16;
  }
  auto stage = [&](int buf){
    char* db = (char*)&Vs[buf][0] + wid * 4096;
    #pragma unroll
    for (int j = 0; j < 4; j++){
      gload_lds16(sp[j], db + j * 1024);
      sp[j] += 64;
    }
  };

  stage(0);

  // Q -> registers: wave-private 32 rows x 256 (B-operand frags; pre-scaled by SC*log2e)
  bf16x8 qreg[2][8];
  #pragma unroll
  for (int qf = 0; qf < 2; qf++)
    #pragma unroll
    for (int kf = 0; kf < 8; kf++)
      qreg[qf][kf] = *(const bf16x8*)(qg + (size_t)(qf * 16 + lr) * 2048 + kf * 32 + lg * 8);

  f32x4 acc[2][16] = {};
  float lpart[2] = {0.f, 0.f};
  int lane16 = lane * 16;
  int vbase = (lr >> 3) * 512 + lg * 128 + (((lr & 7) ^ (lg * 2)) * 16);

  for (int t0 = 0; t0 < 64; t0++){
    int cur = t0 & 1;
    asm volatile("s_waitcnt vmcnt(0)" ::: "memory");   // own V-stage loads (issued a full tile ago)
    __builtin_amdgcn_s_barrier();                      // all waves' V visible; prev compute done
    if (t0 + 1 < 64) stage(cur ^ 1);                   // issue-early: lands during this compute
    const char* Vc = (const char*)Vs[cur];

    // QK^T: A = K frag f = tf*8+kf, straight from packed global (coalesced 1KB/load)
    f32x4 pt[2][2] = {};   // [tf][qf]; row=t, col=q
    __builtin_amdgcn_s_setprio(1);
    #pragma unroll
    for (int kf2 = 0; kf2 < 4; kf2++){
      bf16x8 kE0 = *(const bf16x8*)(kph + (2*kf2    ) * 1024 + lane16);
      bf16x8 kO0 = *(const bf16x8*)(kph + (2*kf2 + 1) * 1024 + lane16);
      bf16x8 kE1 = *(const bf16x8*)(kph + (2*kf2 + 8) * 1024 + lane16);
      bf16x8 kO1 = *(const bf16x8*)(kph + (2*kf2 + 9) * 1024 + lane16);
      pt[0][0] = MFMA(kE0, qreg[0][2*kf2],   pt[0][0]);
      pt[0][1] = MFMA(kE0, qreg[1][2*kf2],   pt[0][1]);
      pt[1][0] = MFMA(kE1, qreg[0][2*kf2],   pt[1][0]);
      pt[1][1] = MFMA(kE1, qreg[1][2*kf2],   pt[1][1]);
      pt[0][0] = MFMA(kO0, qreg[0][2*kf2+1], pt[0][0]);
      pt[0][1] = MFMA(kO0, qreg[1][2*kf2+1], pt[0][1]);
      pt[1][0] = MFMA(kO1, qreg[0][2*kf2+1], pt[1][0]);
      pt[1][1] = MFMA(kO1, qreg[1][2*kf2+1], pt[1][1]);
    }
    __builtin_amdgcn_s_setprio(0);

    // P = exp2(s') directly (scale folded into WQ; constant shift cancels in O/l)
    bf16x8 pa[2];
    #pragma unroll
    for (int qf = 0; qf < 2; qf++){
      float s0 = 0.f, s1 = 0.f;
      #pragma unroll
      for (int tf = 0; tf < 2; tf++)
        #pragma unroll
        for (int r2 = 0; r2 < 4; r2++){
          float e = __builtin_amdgcn_exp2f(pt[tf][qf][r2]);
          pt[tf][qf][r2] = e;
          if (r2 & 1) s1 += e; else s0 += e;
        }
      lpart[qf] += s0 + s1;
      // register butterfly: P^T frag -> PV A-frag (no LDS). dst-first order (verified).
      unsigned A = cvtpk(pt[0][qf][0], pt[0][qf][1]);
      unsigned B = cvtpk(pt[0][qf][2], pt[0][qf][3]);
      unsigned C = cvtpk(pt[1][qf][0], pt[1][qf][1]);
      unsigned D = cvtpk(pt[1][qf][2], pt[1][qf][3]);
      sw32(A, C); sw32(B, D);
      sw16(A, C); sw16(B, D);
      union { unsigned w[4]; bf16x8 v; } cv;
      cv.w[0] = A; cv.w[1] = B; cv.w[2] = C; cv.w[3] = D;
      pa[qf] = cv.v;
    }

    // PV: acc[qrow][c] += P[qrow][t] * V[t][c]  (conflict-free V reads from LDS)
    __builtin_amdgcn_s_setprio(1);
    #pragma unroll
    for (int nf = 0; nf < 16; nf++){
      bf16x8 vf = *(const bf16x8*)(Vc + nf * 1024 + vbase);
      acc[0][nf] = MFMA(pa[0], vf, acc[0][nf]);
      acc[1][nf] = MFMA(pa[1], vf, acc[1][nf]);
    }
    __builtin_amdgcn_s_setprio(0);
    kph += 16384;
  }
  // final l reduction (once per kernel)
  #pragma unroll
  for (int qf = 0; qf < 2; qf++){
    lpart[qf] += __shfl_xor(lpart[qf], 16);
    lpart[qf] += __shfl_xor(lpart[qf], 32);
  }
  // epilogue: O /= l, write u [8192][2048]
  #pragma unroll
  for (int mf = 0; mf < 2; mf++){
    float inv = 1.f / lpart[mf];
    float i4[4];
    #pragma unroll
    for (int r2 = 0; r2 < 4; r2++) i4[r2] = __shfl(inv, lg * 4 + r2);
    #pragma unroll
    for (int nf = 0; nf < 16; nf++)
      #pragma unroll
      for (int r2 = 0; r2 < 4; r2++){
        int s = q0 + wid * 32 + mf * 16 + lg * 4 + r2;
        int c = nf * 16 + lr;
        u[(size_t)(b * 2048 + s) * 2048 + h * 256 + c] = (unsigned short)f2bf(acc[mf][nf][r2] * i4[r2]);
      }
  }
}

// ---------- output projection: [8192,2048] @ [2048,256] + bias -> fp32 ----------
__global__ __launch_bounds__(256, 2) void k_out(const unsigned short* __restrict__ u,
    const unsigned short* __restrict__ woT, const float* __restrict__ bout, float* __restrict__ out){
  __shared__ unsigned short As[64 * 72];
  __shared__ unsigned short Bs[64 * 72];
  int tid = threadIdx.x;
  int lane = tid & 63, wid = tid >> 6;
  int lr = lane & 15, lg = lane >> 4;
  int wm = (wid >> 1) * 32, wn = (wid & 1) * 32;
  int bn = blockIdx.x, bm = blockIdx.y;
  const unsigned short* Ag = u + (size_t)(bm * 64) * 2048;
  const unsigned short* Bg = woT + (size_t)(bn * 64) * 2048;
  f32x4 acc[2][2] = {};
  for (int kt = 0; kt < 32; kt++){
    ushort8 ra[2], rb[2];
    #pragma unroll
    for (int p = 0; p < 2; p++){
      int idx = p * 256 + tid; int row = idx >> 3, ch = idx & 7;
      ra[p] = *(const ushort8*)(Ag + (size_t)row * 2048 + kt*64 + ch*8);
      rb[p] = *(const ushort8*)(Bg + (size_t)row * 2048 + kt*64 + ch*8);
    }
    __syncthreads();
    #pragma unroll
    for (int p = 0; p < 2; p++){
      int idx = p * 256 + tid; int row = idx >> 3, ch = idx & 7;
      *(ushort8*)(As + row * 72 + ch * 8) = ra[p];
      *(ushort8*)(Bs + row * 72 + ch * 8) = rb[p];
    }
    __syncthreads();
    #pragma unroll
    for (int kf = 0; kf < 2; kf++){
      bf16x8 a0 = *(const bf16x8*)(As + (wm + lr) * 72      + kf*32 + lg*8);
      bf16x8 a1 = *(const bf16x8*)(As + (wm + 16 + lr) * 72 + kf*32 + lg*8);
      bf16x8 b0 = *(const bf16x8*)(Bs + (wn + lr) * 72      + kf*32 + lg*8);
      bf16x8 b1 = *(const bf16x8*)(Bs + (wn + 16 + lr) * 72 + kf*32 + lg*8);
      acc[0][0] = MFMA(a0, b0, acc[0][0]); acc[0][1] = MFMA(a0, b1, acc[0][1]);
      acc[1][0] = MFMA(a1, b0, acc[1][0]); acc[1][1] = MFMA(a1, b1, acc[1][1]);
    }
  }
  #pragma unroll
  for (int mf = 0; mf < 2; mf++)
    #pragma unroll
    for (int nf = 0; nf < 2; nf++){
      int mg = bm*64 + wm + mf*16 + lg*4;
      int ng = bn*64 + wn + nf*16 + lr;
      #pragma unroll
      for (int r2 = 0; r2 < 4; r2++) out[(size_t)(mg + r2) * 256 + ng] = acc[mf][nf][r2] + bout[ng];
    }
}

extern "C" void kernel_launch(void* const* d_in, const int* in_sizes, int n_in,
                              void* d_out, int out_size, void* d_ws, size_t ws_size,
                              hipStream_t stream){
  const float* v    = (const float*)d_in[0];
  const float* WQ   = (const float*)d_in[1];
  const float* WK   = (const float*)d_in[2];
  const float* WV   = (const float*)d_in[3];
  const float* Wout = (const float*)d_in[4];
  const float* bout = (const float*)d_in[5];
  char* ws = (char*)d_ws;
  unsigned short* vb  = (unsigned short*)(ws);                     // v bf16      [8192][256]   4 MB
  unsigned short* wT  = (unsigned short*)(ws + (4u  << 20));       // WQ/WK/WV^T  [3][2048][256] 3 MB (WQ pre-scaled)
  unsigned short* woT = (unsigned short*)(ws + (7u  << 20));       // Wout^T      [256][2048]   1 MB
  unsigned short* qb  = (unsigned short*)(ws + (8u  << 20));       // q  [8192][2048] 32 MB
  char*           kpB = (char*)          (ws + (40u << 20));       // K packed frags  32 MB
  unsigned short* vTb = (unsigned short*)(ws + (72u << 20));       // vT [b,h,c,s]   32 MB
  unsigned short* ub  = (unsigned short*)(ws + (104u << 20));      // u  [8192][2048] 32 MB
  float* out = (float*)d_out;

  k_cvt<<<2048, 256, 0, stream>>>(v, vb, 2097152);
  k_tr4<<<2048, dim3(32, 8), 0, stream>>>(WQ, WK, WV, Wout, wT, woT);
  k_qkv<<<dim3(16, 64, 3), 256, 0, stream>>>(vb, wT, qb, kpB, vTb);
  k_attn<<<512, 256, 0, stream>>>(qb, kpB, vTb, ub);
  k_out<<<dim3(4, 128), 256, 0, stream>>>(ub, woT, bout, out);
}

// Round 9
// 219.058 us; speedup vs baseline: 1.4276x; 1.4276x over previous
//
#include <hip/hip_runtime.h>
#include <hip/hip_bf16.h>

typedef __bf16 bf16x8 __attribute__((ext_vector_type(8)));
typedef float f32x4 __attribute__((ext_vector_type(4)));
typedef float f32x16 __attribute__((ext_vector_type(16)));
typedef unsigned short ushort8 __attribute__((ext_vector_type(8)));

#define DEVINL static __device__ __forceinline__

DEVINL unsigned f2bf(float f){
  unsigned u = __float_as_uint(f);
  return (u + 0x7fffu + ((u >> 16) & 1u)) >> 16;
}

DEVINL f32x4 MFMA(bf16x8 a, bf16x8 b, f32x4 c){
  return __builtin_amdgcn_mfma_f32_16x16x32_bf16(a, b, c, 0, 0, 0);
}
DEVINL f32x16 MFMA32(bf16x8 a, bf16x8 b, f32x16 c){
  return __builtin_amdgcn_mfma_f32_32x32x16_bf16(a, b, c, 0, 0, 0);
}

typedef const __attribute__((address_space(1))) unsigned int* gas_t;
typedef __attribute__((address_space(3))) unsigned int* las_t;
DEVINL void gload_lds16(const void* g, void* l){
  __builtin_amdgcn_global_load_lds((gas_t)g, (las_t)l, 16, 0, 0);
}

// sw32(a,b): a=[a.row0, b.row0], b=[a.row1, b.row1]   (row = 32 lanes)
DEVINL unsigned cvtpk(float lo, float hi){
  unsigned r; asm("v_cvt_pk_bf16_f32 %0, %1, %2" : "=v"(r) : "v"(lo), "v"(hi)); return r;
}
DEVINL void sw32(unsigned &a, unsigned &b){ asm("v_permlane32_swap_b32 %0, %1" : "+v"(a), "+v"(b)); }

// ---------- fp32 -> bf16 pack (n multiple of 4) ----------
__global__ void k_cvt(const float* __restrict__ s, unsigned short* __restrict__ d, int n){
  int i = (blockIdx.x * blockDim.x + threadIdx.x) * 4;
  if (i >= n) return;
  float4 v = *(const float4*)(s + i);
  ushort4 o;
  o.x = (unsigned short)f2bf(v.x); o.y = (unsigned short)f2bf(v.y);
  o.z = (unsigned short)f2bf(v.z); o.w = (unsigned short)f2bf(v.w);
  *(ushort4*)(d + i) = o;
}

// ---------- fused transposes; WQ additionally pre-scaled by SC*log2(e) ----------
__global__ void k_tr4(const float* __restrict__ WQ, const float* __restrict__ WK,
                      const float* __restrict__ WV, const float* __restrict__ Wout,
                      unsigned short* __restrict__ wT, unsigned short* __restrict__ woT){
  __shared__ float t[32][33];
  int id = blockIdx.x;
  const float* s; unsigned short* d; int R, C, tile;
  float scl = 1.0f;
  if (id < 1536){
    int z = id >> 9; tile = id & 511;
    s = (z == 0) ? WQ : ((z == 1) ? WK : WV);
    if (z == 0) scl = 0.25503510f;   // (1/sqrt(32)) * log2(e) folded into WQ
    d = wT + z * 524288; R = 256; C = 2048;
  } else {
    tile = id - 1536; s = Wout; d = woT; R = 2048; C = 256;
  }
  int tilesX = C >> 5;
  int c0 = (tile % tilesX) * 32, r0 = (tile / tilesX) * 32;
  int tx = threadIdx.x, ty = threadIdx.y;
  #pragma unroll
  for (int k2 = 0; k2 < 4; k2++) t[ty + 8*k2][tx] = s[(r0 + ty + 8*k2) * C + c0 + tx];
  __syncthreads();
  #pragma unroll
  for (int k2 = 0; k2 < 4; k2++) d[(c0 + ty + 8*k2) * R + r0 + tx] = (unsigned short)f2bf(t[tx][ty + 8*k2] * scl);
}

// ---------- QKV projection: [8192,256] @ [256,2048] -> q,k [8192,2048], val -> vT[b,h,c,s] ----------
__global__ __launch_bounds__(256, 2) void k_qkv(const unsigned short* __restrict__ vb,
    const unsigned short* __restrict__ wT,
    unsigned short* __restrict__ qo, unsigned short* __restrict__ ko, unsigned short* __restrict__ vTo){
  __shared__ unsigned short As[128 * 72];
  __shared__ unsigned short Bs[128 * 72];
  int tid = threadIdx.x;
  int lane = tid & 63, wid = tid >> 6;
  int lr = lane & 15, lg = lane >> 4;
  int wm = (wid >> 1) * 64, wn = (wid & 1) * 64;
  int bn = blockIdx.x, bm = blockIdx.y, z = blockIdx.z;

  const unsigned short* Ag = vb + (bm * 128) * 256;
  const unsigned short* Bg = wT + z * (2048 * 256) + (bn * 128) * 256;

  f32x4 acc[4][4] = {};
  for (int kt = 0; kt < 4; kt++){
    ushort8 ra[4], rb[4];
    #pragma unroll
    for (int p = 0; p < 4; p++){
      int idx = p * 256 + tid; int row = idx >> 3, ch = idx & 7;
      ra[p] = *(const ushort8*)(Ag + row * 256 + kt * 64 + ch * 8);
      rb[p] = *(const ushort8*)(Bg + row * 256 + kt * 64 + ch * 8);
    }
    __syncthreads();
    #pragma unroll
    for (int p = 0; p < 4; p++){
      int idx = p * 256 + tid; int row = idx >> 3, ch = idx & 7;
      *(ushort8*)(As + row * 72 + ch * 8) = ra[p];
      *(ushort8*)(Bs + row * 72 + ch * 8) = rb[p];
    }
    __syncthreads();
    #pragma unroll
    for (int kf = 0; kf < 2; kf++){
      bf16x8 af[4], bfr[4];
      #pragma unroll
      for (int mf = 0; mf < 4; mf++) af[mf]  = *(const bf16x8*)(As + (wm + mf*16 + lr) * 72 + kf*32 + lg*8);
      #pragma unroll
      for (int nf = 0; nf < 4; nf++) bfr[nf] = *(const bf16x8*)(Bs + (wn + nf*16 + lr) * 72 + kf*32 + lg*8);
      #pragma unroll
      for (int mf = 0; mf < 4; mf++)
        #pragma unroll
        for (int nf = 0; nf < 4; nf++)
          acc[mf][nf] = MFMA(af[mf], bfr[nf], acc[mf][nf]);
    }
  }
  if (z < 2){
    unsigned short* dst = z ? ko : qo;
    #pragma unroll
    for (int mf = 0; mf < 4; mf++)
      #pragma unroll
      for (int nf = 0; nf < 4; nf++){
        int mg = bm*128 + wm + mf*16 + lg*4;
        int ng = bn*128 + wn + nf*16 + lr;
        #pragma unroll
        for (int r2 = 0; r2 < 4; r2++) dst[(mg + r2) * 2048 + ng] = (unsigned short)f2bf(acc[mf][nf][r2]);
      }
  } else {
    #pragma unroll
    for (int mf = 0; mf < 4; mf++)
      #pragma unroll
      for (int nf = 0; nf < 4; nf++){
        int mg = bm*128 + wm + mf*16 + lg*4;
        int ng = bn*128 + wn + nf*16 + lr;
        int bb = mg >> 11, s = mg & 2047, hh = ng >> 8, cc = ng & 255;
        uint2 w;
        w.x = f2bf(acc[mf][nf][0]) | (f2bf(acc[mf][nf][1]) << 16);
        w.y = f2bf(acc[mf][nf][2]) | (f2bf(acc[mf][nf][3]) << 16);
        *(uint2*)(vTo + (size_t)((bb*8 + hh) * 256 + cc) * 2048 + s) = w;
      }
  }
}

// ---------- flash attention: 4 waves/block, R7 LDS dbuf skeleton, 32x32x16 MFMA ----------
// Layouts (derived from verified C/D map col=l&31, row=(r&3)+8*(r>>2)+4*(l>>5)):
//   A-frag: m=l&31, k=8*(l>>5)+j ; B-frag: n=l&31, k=8*(l>>5)+j
// QK^T swapped: mfma(A=K[t][c], B=Q[c][q]) -> pt[r] = S^T[t=(r&3)+8(r>>2)+4hi][q=l31]
// butterfly: w_i=cvtpk(p2i,p2i+1); sw32(w0,w2),sw32(w1,w3) -> pa0 (t0..15);
//            sw32(w4,w6),sw32(w5,w7) -> pa1 (t16..31)   [element-verified]
// K LDS (unchanged): byte(t,c)=t*512+((c/8)^(t&7))*16 -> 32-row reads conflict-free
// V LDS (unchanged): byte(c,ts)=(c>>3)*512+ts*128+((c&7)^2ts)*16 -> conflict-free
__global__ __launch_bounds__(256, 2) void k_attn(const unsigned short* __restrict__ q,
    const unsigned short* __restrict__ kk, const unsigned short* __restrict__ vT,
    unsigned short* __restrict__ u){
  __shared__ unsigned short Ks[2][8192];
  __shared__ unsigned short Vs[2][8192];
  int tid = threadIdx.x;
  int lane = tid & 63, wid = tid >> 6;
  int l31 = lane & 31, hi = lane >> 5;
  // XCD-chunked swizzle
  int g = (blockIdx.x & 7) * 64 + (blockIdx.x >> 3);
  int bh = g >> 4, qt = g & 15;
  int b = bh >> 3, h = bh & 7;
  int q0 = qt * 128;

  const char* kgB = (const char*)(kk + (size_t)b * 2048 * 2048 + h * 256);
  const char* vgB = (const char*)(vT + (size_t)(b * 8 + h) * 256 * 2048);
  const unsigned short* qg = q + (size_t)(b * 2048 + q0 + wid * 32) * 2048 + h * 256;

  // staging identical to R7: waves 0,1 -> K, waves 2,3 -> V; 8x 1KB chunks each
  const char* sp[8];
  bool isK = wid < 2;
  long stepB = isK ? 131072 : 64;
  #pragma unroll
  for (int j = 0; j < 8; j++){
    if (isK){
      int c = wid * 512 + j * 64 + lane;
      int row = c >> 5, slot = c & 31;
      sp[j] = kgB + (size_t)row * 4096 + ((slot ^ (row & 7)) * 16);
    } else {
      int c2 = (wid - 2) * 512 + j * 64 + lane;
      int blk = c2 >> 5, ts = (c2 >> 3) & 3, low3 = c2 & 7;
      int crow = blk * 8 + (low3 ^ (ts * 2));
      sp[j] = vgB + (size_t)crow * 4096 + ts * 16;
    }
  }
  int wbase = (wid & 1) * 8192;
  auto stage = [&](int buf){
    char* db = (char*)(isK ? &Ks[buf][0] : &Vs[buf][0]) + wbase;
    #pragma unroll
    for (int j = 0; j < 8; j++){
      gload_lds16(sp[j], db + j * 1024);
      sp[j] += stepB;
    }
  };

  stage(0);

  // Q -> registers: B-frags; qreg[s] = Q[q=l31][c = s*16 + hi*8 + 0..7]
  bf16x8 qreg[16];
  #pragma unroll
  for (int s = 0; s < 16; s++)
    qreg[s] = *(const bf16x8*)(qg + (size_t)l31 * 2048 + s * 16 + hi * 8);

  f32x16 acc[8] = {};
  float lpart = 0.f;

  // loop-invariant addressing
  int kb2 = l31 * 512 + ((hi ^ (lane & 1)) << 4);   // K: + ((s ^ xh) << 5) per step
  int xh  = (lane >> 1) & 3;
  int vb0 = (l31 >> 3) * 512 + hi * 128 + (((lane & 7) ^ (2 * hi)) * 16);           // step0: ts=hi
  int vb1 = (l31 >> 3) * 512 + (2 + hi) * 128 + (((lane & 7) ^ (4 + 2 * hi)) * 16); // step1: ts=2+hi

  for (int t0 = 0; t0 < 64; t0++){
    int cur = t0 & 1;
    asm volatile("s_waitcnt vmcnt(0)" ::: "memory");   // own stage loads (issued a full tile ago)
    __builtin_amdgcn_s_barrier();                      // all waves' loads visible; prev compute done
    if (t0 + 1 < 64) stage(cur ^ 1);                   // issue-early: lands during this compute
    const char* Kc = (const char*)Ks[cur];
    const char* Vc = (const char*)Vs[cur];

    // QK^T: 16 chained 32x32x16 MFMAs over c
    f32x16 pt = {};
    __builtin_amdgcn_s_setprio(1);
    #pragma unroll
    for (int s = 0; s < 16; s++){
      bf16x8 ka = *(const bf16x8*)(Kc + kb2 + ((s ^ xh) << 5));
      pt = MFMA32(ka, qreg[s], pt);
    }
    __builtin_amdgcn_s_setprio(0);

    // softmax: P = exp2(s') (scale folded into WQ; constant shift cancels in O/l)
    float e[16];
    float s0 = 0.f, s1 = 0.f;
    #pragma unroll
    for (int r = 0; r < 16; r++){
      float ev = __builtin_amdgcn_exp2f(pt[r]);
      e[r] = ev;
      if (r & 1) s1 += ev; else s0 += ev;
    }
    lpart += s0 + s1;
    // butterfly -> PV A-frags (register-only)
    unsigned w0 = cvtpk(e[0],  e[1]),  w1 = cvtpk(e[2],  e[3]);
    unsigned w2 = cvtpk(e[4],  e[5]),  w3 = cvtpk(e[6],  e[7]);
    unsigned w4 = cvtpk(e[8],  e[9]),  w5 = cvtpk(e[10], e[11]);
    unsigned w6 = cvtpk(e[12], e[13]), w7 = cvtpk(e[14], e[15]);
    sw32(w0, w2); sw32(w1, w3);
    sw32(w4, w6); sw32(w5, w7);
    union { unsigned w[4]; bf16x8 v; } cv0, cv1;
    cv0.w[0] = w0; cv0.w[1] = w1; cv0.w[2] = w2; cv0.w[3] = w3;
    cv1.w[0] = w4; cv1.w[1] = w5; cv1.w[2] = w6; cv1.w[3] = w7;
    bf16x8 pa0 = cv0.v;   // t = 0..15
    bf16x8 pa1 = cv1.v;   // t = 16..31

    // PV: acc[nf] over 8 c-tiles, 2 K-steps each
    __builtin_amdgcn_s_setprio(1);
    #pragma unroll
    for (int nf = 0; nf < 8; nf++){
      bf16x8 v0 = *(const bf16x8*)(Vc + nf * 2048 + vb0);
      bf16x8 v1 = *(const bf16x8*)(Vc + nf * 2048 + vb1);
      acc[nf] = MFMA32(pa0, v0, acc[nf]);
      acc[nf] = MFMA32(pa1, v1, acc[nf]);
    }
    __builtin_amdgcn_s_setprio(0);
  }
  // final l reduction: lane's partial covers q=l31 over its t-half
  lpart += __shfl_xor(lpart, 32);
  float inv = 1.f / lpart;
  float iv[16];
  #pragma unroll
  for (int r = 0; r < 16; r++){
    int qq = (r & 3) + 8 * (r >> 2) + 4 * hi;
    iv[r] = __shfl(inv, qq);
  }
  // epilogue: O /= l, write u [8192][2048]
  unsigned short* ug = u + (size_t)(b * 2048 + q0 + wid * 32) * 2048 + h * 256;
  #pragma unroll
  for (int nf = 0; nf < 8; nf++)
    #pragma unroll
    for (int r = 0; r < 16; r++){
      int qq = (r & 3) + 8 * (r >> 2) + 4 * hi;
      ug[(size_t)qq * 2048 + nf * 32 + l31] = (unsigned short)f2bf(acc[nf][r] * iv[r]);
    }
}

// ---------- output projection: [8192,2048] @ [2048,256] + bias -> fp32 ----------
__global__ __launch_bounds__(256, 2) void k_out(const unsigned short* __restrict__ u,
    const unsigned short* __restrict__ woT, const float* __restrict__ bout, float* __restrict__ out){
  __shared__ unsigned short As[64 * 72];
  __shared__ unsigned short Bs[64 * 72];
  int tid = threadIdx.x;
  int lane = tid & 63, wid = tid >> 6;
  int lr = lane & 15, lg = lane >> 4;
  int wm = (wid >> 1) * 32, wn = (wid & 1) * 32;
  int bn = blockIdx.x, bm = blockIdx.y;
  const unsigned short* Ag = u + (size_t)(bm * 64) * 2048;
  const unsigned short* Bg = woT + (size_t)(bn * 64) * 2048;
  f32x4 acc[2][2] = {};
  for (int kt = 0; kt < 32; kt++){
    ushort8 ra[2], rb[2];
    #pragma unroll
    for (int p = 0; p < 2; p++){
      int idx = p * 256 + tid; int row = idx >> 3, ch = idx & 7;
      ra[p] = *(const ushort8*)(Ag + (size_t)row * 2048 + kt*64 + ch*8);
      rb[p] = *(const ushort8*)(Bg + (size_t)row * 2048 + kt*64 + ch*8);
    }
    __syncthreads();
    #pragma unroll
    for (int p = 0; p < 2; p++){
      int idx = p * 256 + tid; int row = idx >> 3, ch = idx & 7;
      *(ushort8*)(As + row * 72 + ch * 8) = ra[p];
      *(ushort8*)(Bs + row * 72 + ch * 8) = rb[p];
    }
    __syncthreads();
    #pragma unroll
    for (int kf = 0; kf < 2; kf++){
      bf16x8 a0 = *(const bf16x8*)(As + (wm + lr) * 72      + kf*32 + lg*8);
      bf16x8 a1 = *(const bf16x8*)(As + (wm + 16 + lr) * 72 + kf*32 + lg*8);
      bf16x8 b0 = *(const bf16x8*)(Bs + (wn + lr) * 72      + kf*32 + lg*8);
      bf16x8 b1 = *(const bf16x8*)(Bs + (wn + 16 + lr) * 72 + kf*32 + lg*8);
      acc[0][0] = MFMA(a0, b0, acc[0][0]); acc[0][1] = MFMA(a0, b1, acc[0][1]);
      acc[1][0] = MFMA(a1, b0, acc[1][0]); acc[1][1] = MFMA(a1, b1, acc[1][1]);
    }
  }
  #pragma unroll
  for (int mf = 0; mf < 2; mf++)
    #pragma unroll
    for (int nf = 0; nf < 2; nf++){
      int mg = bm*64 + wm + mf*16 + lg*4;
      int ng = bn*64 + wn + nf*16 + lr;
      #pragma unroll
      for (int r2 = 0; r2 < 4; r2++) out[(size_t)(mg + r2) * 256 + ng] = acc[mf][nf][r2] + bout[ng];
    }
}

extern "C" void kernel_launch(void* const* d_in, const int* in_sizes, int n_in,
                              void* d_out, int out_size, void* d_ws, size_t ws_size,
                              hipStream_t stream){
  const float* v    = (const float*)d_in[0];
  const float* WQ   = (const float*)d_in[1];
  const float* WK   = (const float*)d_in[2];
  const float* WV   = (const float*)d_in[3];
  const float* Wout = (const float*)d_in[4];
  const float* bout = (const float*)d_in[5];
  char* ws = (char*)d_ws;
  unsigned short* vb  = (unsigned short*)(ws);                     // v bf16      [8192][256]   4 MB
  unsigned short* wT  = (unsigned short*)(ws + (4u  << 20));       // WQ/WK/WV^T  [3][2048][256] 3 MB (WQ pre-scaled)
  unsigned short* woT = (unsigned short*)(ws + (7u  << 20));       // Wout^T      [256][2048]   1 MB
  unsigned short* qb  = (unsigned short*)(ws + (8u  << 20));       // q  [8192][2048] 32 MB
  unsigned short* kb  = (unsigned short*)(ws + (40u << 20));       // k  [8192][2048] 32 MB
  unsigned short* vTb = (unsigned short*)(ws + (72u << 20));       // vT [b,h,c,s]   32 MB
  unsigned short* ub  = (unsigned short*)(ws + (104u << 20));      // u  [8192][2048] 32 MB
  float* out = (float*)d_out;

  k_cvt<<<2048, 256, 0, stream>>>(v, vb, 2097152);
  k_tr4<<<2048, dim3(32, 8), 0, stream>>>(WQ, WK, WV, Wout, wT, woT);
  k_qkv<<<dim3(16, 64, 3), 256, 0, stream>>>(vb, wT, qb, kb, vTb);
  k_attn<<<512, 256, 0, stream>>>(qb, kb, vTb, ub);
  k_out<<<dim3(4, 128), 256, 0, stream>>>(ub, woT, bout, out);
}

// Round 12
// 215.678 us; speedup vs baseline: 1.4500x; 1.0157x over previous
//
#include <hip/hip_runtime.h>
#include <hip/hip_bf16.h>

typedef __bf16 bf16x8 __attribute__((ext_vector_type(8)));
typedef float f32x4 __attribute__((ext_vector_type(4)));
typedef float f32x16 __attribute__((ext_vector_type(16)));
typedef unsigned short ushort8 __attribute__((ext_vector_type(8)));

#define DEVINL static __device__ __forceinline__

DEVINL unsigned f2bf(float f){
  unsigned u = __float_as_uint(f);
  return (u + 0x7fffu + ((u >> 16) & 1u)) >> 16;
}

DEVINL f32x4 MFMA(bf16x8 a, bf16x8 b, f32x4 c){
  return __builtin_amdgcn_mfma_f32_16x16x32_bf16(a, b, c, 0, 0, 0);
}
DEVINL f32x16 MFMA32(bf16x8 a, bf16x8 b, f32x16 c){
  return __builtin_amdgcn_mfma_f32_32x32x16_bf16(a, b, c, 0, 0, 0);
}

typedef const __attribute__((address_space(1))) unsigned int* gas_t;
typedef __attribute__((address_space(3))) unsigned int* las_t;
DEVINL void gload_lds16(const void* g, void* l){
  __builtin_amdgcn_global_load_lds((gas_t)g, (las_t)l, 16, 0, 0);
}

// sw32(a,b): a=[a.row0, b.row0], b=[a.row1, b.row1]   (row = 32 lanes)
DEVINL unsigned cvtpk(float lo, float hi){
  unsigned r; asm("v_cvt_pk_bf16_f32 %0, %1, %2" : "=v"(r) : "v"(lo), "v"(hi)); return r;
}
DEVINL void sw32(unsigned &a, unsigned &b){ asm("v_permlane32_swap_b32 %0, %1" : "+v"(a), "+v"(b)); }

// ---------- fused prep: fp32->bf16 pack of v  +  weight transposes (WQ pre-scaled) ----------
// grid 4096 x (32,8): blocks 0..2047 = cvt (2M elems), 2048..4095 = transposes
__global__ void k_prep(const float* __restrict__ v, const float* __restrict__ WQ,
                       const float* __restrict__ WK, const float* __restrict__ WV,
                       const float* __restrict__ Wout,
                       unsigned short* __restrict__ vb,
                       unsigned short* __restrict__ wT, unsigned short* __restrict__ woT){
  int tid = threadIdx.y * 32 + threadIdx.x;
  int id = blockIdx.x;
  if (id < 2048){
    int i = (id * 256 + tid) * 4;
    float4 x = *(const float4*)(v + i);
    ushort4 o;
    o.x = (unsigned short)f2bf(x.x); o.y = (unsigned short)f2bf(x.y);
    o.z = (unsigned short)f2bf(x.z); o.w = (unsigned short)f2bf(x.w);
    *(ushort4*)(vb + i) = o;
    return;
  }
  __shared__ float t[32][33];
  int id2 = id - 2048;
  const float* s; unsigned short* d; int R, C, tile;
  float scl = 1.0f;
  if (id2 < 1536){
    int z = id2 >> 9; tile = id2 & 511;
    s = (z == 0) ? WQ : ((z == 1) ? WK : WV);
    if (z == 0) scl = 0.25503510f;   // (1/sqrt(32)) * log2(e) folded into WQ
    d = wT + z * 524288; R = 256; C = 2048;
  } else {
    tile = id2 - 1536; s = Wout; d = woT; R = 2048; C = 256;
  }
  int tilesX = C >> 5;
  int c0 = (tile % tilesX) * 32, r0 = (tile / tilesX) * 32;
  int tx = threadIdx.x, ty = threadIdx.y;
  #pragma unroll
  for (int k2 = 0; k2 < 4; k2++) t[ty + 8*k2][tx] = s[(r0 + ty + 8*k2) * C + c0 + tx];
  __syncthreads();
  #pragma unroll
  for (int k2 = 0; k2 < 4; k2++) d[(c0 + ty + 8*k2) * R + r0 + tx] = (unsigned short)f2bf(t[tx][ty + 8*k2] * scl);
}

// ---------- QKV projection: [8192,256] @ [256,2048] -> q,k [8192,2048], val -> vT[b,h,c,s] ----------
__global__ __launch_bounds__(256, 2) void k_qkv(const unsigned short* __restrict__ vb,
    const unsigned short* __restrict__ wT,
    unsigned short* __restrict__ qo, unsigned short* __restrict__ ko, unsigned short* __restrict__ vTo){
  __shared__ unsigned short As[128 * 72];
  __shared__ unsigned short Bs[128 * 72];
  int tid = threadIdx.x;
  int lane = tid & 63, wid = tid >> 6;
  int lr = lane & 15, lg = lane >> 4;
  int wm = (wid >> 1) * 64, wn = (wid & 1) * 64;
  int bn = blockIdx.x, bm = blockIdx.y, z = blockIdx.z;

  const unsigned short* Ag = vb + (bm * 128) * 256;
  const unsigned short* Bg = wT + z * (2048 * 256) + (bn * 128) * 256;

  f32x4 acc[4][4] = {};
  for (int kt = 0; kt < 4; kt++){
    ushort8 ra[4], rb[4];
    #pragma unroll
    for (int p = 0; p < 4; p++){
      int idx = p * 256 + tid; int row = idx >> 3, ch = idx & 7;
      ra[p] = *(const ushort8*)(Ag + row * 256 + kt * 64 + ch * 8);
      rb[p] = *(const ushort8*)(Bg + row * 256 + kt * 64 + ch * 8);
    }
    __syncthreads();
    #pragma unroll
    for (int p = 0; p < 4; p++){
      int idx = p * 256 + tid; int row = idx >> 3, ch = idx & 7;
      *(ushort8*)(As + row * 72 + ch * 8) = ra[p];
      *(ushort8*)(Bs + row * 72 + ch * 8) = rb[p];
    }
    __syncthreads();
    #pragma unroll
    for (int kf = 0; kf < 2; kf++){
      bf16x8 af[4], bfr[4];
      #pragma unroll
      for (int mf = 0; mf < 4; mf++) af[mf]  = *(const bf16x8*)(As + (wm + mf*16 + lr) * 72 + kf*32 + lg*8);
      #pragma unroll
      for (int nf = 0; nf < 4; nf++) bfr[nf] = *(const bf16x8*)(Bs + (wn + nf*16 + lr) * 72 + kf*32 + lg*8);
      #pragma unroll
      for (int mf = 0; mf < 4; mf++)
        #pragma unroll
        for (int nf = 0; nf < 4; nf++)
          acc[mf][nf] = MFMA(af[mf], bfr[nf], acc[mf][nf]);
    }
  }
  if (z < 2){
    unsigned short* dst = z ? ko : qo;
    #pragma unroll
    for (int mf = 0; mf < 4; mf++)
      #pragma unroll
      for (int nf = 0; nf < 4; nf++){
        int mg = bm*128 + wm + mf*16 + lg*4;
        int ng = bn*128 + wn + nf*16 + lr;
        #pragma unroll
        for (int r2 = 0; r2 < 4; r2++) dst[(mg + r2) * 2048 + ng] = (unsigned short)f2bf(acc[mf][nf][r2]);
      }
  } else {
    #pragma unroll
    for (int mf = 0; mf < 4; mf++)
      #pragma unroll
      for (int nf = 0; nf < 4; nf++){
        int mg = bm*128 + wm + mf*16 + lg*4;
        int ng = bn*128 + wn + nf*16 + lr;
        int bb = mg >> 11, s = mg & 2047, hh = ng >> 8, cc = ng & 255;
        uint2 w;
        w.x = f2bf(acc[mf][nf][0]) | (f2bf(acc[mf][nf][1]) << 16);
        w.y = f2bf(acc[mf][nf][2]) | (f2bf(acc[mf][nf][3]) << 16);
        *(uint2*)(vTo + (size_t)((bb*8 + hh) * 256 + cc) * 2048 + s) = w;
      }
  }
}

// ---------- flash attention: 4 waves/block, R9 skeleton (proven), 32x32x16 MFMA ----------
// (byte-identical to the R9 passing version; the T15 3-deep pipeline was abandoned after
//  two unexplained correctness failures — sync-structure edits need race screening this
//  loop cannot provide.)
__global__ __launch_bounds__(256, 2) void k_attn(const unsigned short* __restrict__ q,
    const unsigned short* __restrict__ kk, const unsigned short* __restrict__ vT,
    unsigned short* __restrict__ u){
  __shared__ unsigned short Ks[2][8192];
  __shared__ unsigned short Vs[2][8192];
  int tid = threadIdx.x;
  int lane = tid & 63, wid = tid >> 6;
  int l31 = lane & 31, hi = lane >> 5;
  // XCD-chunked swizzle
  int g = (blockIdx.x & 7) * 64 + (blockIdx.x >> 3);
  int bh = g >> 4, qt = g & 15;
  int b = bh >> 3, h = bh & 7;
  int q0 = qt * 128;

  const char* kgB = (const char*)(kk + (size_t)b * 2048 * 2048 + h * 256);
  const char* vgB = (const char*)(vT + (size_t)(b * 8 + h) * 256 * 2048);
  const unsigned short* qg = q + (size_t)(b * 2048 + q0 + wid * 32) * 2048 + h * 256;

  // staging: waves 0,1 -> K, waves 2,3 -> V; 8x 1KB chunks each per tile
  const char* sp[8];
  bool isK = wid < 2;
  long stepB = isK ? 131072 : 64;
  #pragma unroll
  for (int j = 0; j < 8; j++){
    if (isK){
      int c = wid * 512 + j * 64 + lane;
      int row = c >> 5, slot = c & 31;
      sp[j] = kgB + (size_t)row * 4096 + ((slot ^ (row & 7)) * 16);
    } else {
      int c2 = (wid - 2) * 512 + j * 64 + lane;
      int blk = c2 >> 5, ts = (c2 >> 3) & 3, low3 = c2 & 7;
      int crow = blk * 8 + (low3 ^ (ts * 2));
      sp[j] = vgB + (size_t)crow * 4096 + ts * 16;
    }
  }
  int wbase = (wid & 1) * 8192;
  auto stage = [&](int buf){
    char* db = (char*)(isK ? &Ks[buf][0] : &Vs[buf][0]) + wbase;
    #pragma unroll
    for (int j = 0; j < 8; j++){
      gload_lds16(sp[j], db + j * 1024);
      sp[j] += stepB;
    }
  };

  stage(0);

  // Q -> registers: B-frags; qreg[s] = Q[q=l31][c = s*16 + hi*8 + 0..7]
  bf16x8 qreg[16];
  #pragma unroll
  for (int s = 0; s < 16; s++)
    qreg[s] = *(const bf16x8*)(qg + (size_t)l31 * 2048 + s * 16 + hi * 8);

  f32x16 acc[8] = {};
  float lpart = 0.f;

  // loop-invariant addressing
  int kb2 = l31 * 512 + ((hi ^ (lane & 1)) << 4);   // K: + ((s ^ xh) << 5) per step
  int xh  = (lane >> 1) & 3;
  int vb0 = (l31 >> 3) * 512 + hi * 128 + (((lane & 7) ^ (2 * hi)) * 16);           // step0: ts=hi
  int vb1 = (l31 >> 3) * 512 + (2 + hi) * 128 + (((lane & 7) ^ (4 + 2 * hi)) * 16); // step1: ts=2+hi

  for (int t0 = 0; t0 < 64; t0++){
    int cur = t0 & 1;
    asm volatile("s_waitcnt vmcnt(0)" ::: "memory");   // own stage loads (issued a full tile ago)
    __builtin_amdgcn_s_barrier();                      // all waves' loads visible; prev compute done
    if (t0 + 1 < 64) stage(cur ^ 1);                   // issue-early: lands during this compute
    const char* Kc = (const char*)Ks[cur];
    const char* Vc = (const char*)Vs[cur];

    // QK^T: 16 chained 32x32x16 MFMAs over c
    f32x16 pt = {};
    __builtin_amdgcn_s_setprio(1);
    #pragma unroll
    for (int s = 0; s < 16; s++){
      bf16x8 ka = *(const bf16x8*)(Kc + kb2 + ((s ^ xh) << 5));
      pt = MFMA32(ka, qreg[s], pt);
    }
    __builtin_amdgcn_s_setprio(0);

    // softmax: P = exp2(s') (scale folded into WQ; constant shift cancels in O/l)
    float e[16];
    float s0 = 0.f, s1 = 0.f;
    #pragma unroll
    for (int r = 0; r < 16; r++){
      float ev = __builtin_amdgcn_exp2f(pt[r]);
      e[r] = ev;
      if (r & 1) s1 += ev; else s0 += ev;
    }
    lpart += s0 + s1;
    // butterfly -> PV A-frags (register-only)
    unsigned w0 = cvtpk(e[0],  e[1]),  w1 = cvtpk(e[2],  e[3]);
    unsigned w2 = cvtpk(e[4],  e[5]),  w3 = cvtpk(e[6],  e[7]);
    unsigned w4 = cvtpk(e[8],  e[9]),  w5 = cvtpk(e[10], e[11]);
    unsigned w6 = cvtpk(e[12], e[13]), w7 = cvtpk(e[14], e[15]);
    sw32(w0, w2); sw32(w1, w3);
    sw32(w4, w6); sw32(w5, w7);
    union { unsigned w[4]; bf16x8 v; } cv0, cv1;
    cv0.w[0] = w0; cv0.w[1] = w1; cv0.w[2] = w2; cv0.w[3] = w3;
    cv1.w[0] = w4; cv1.w[1] = w5; cv1.w[2] = w6; cv1.w[3] = w7;
    bf16x8 pa0 = cv0.v;   // t = 0..15
    bf16x8 pa1 = cv1.v;   // t = 16..31

    // PV: acc[nf] over 8 c-tiles, 2 K-steps each
    __builtin_amdgcn_s_setprio(1);
    #pragma unroll
    for (int nf = 0; nf < 8; nf++){
      bf16x8 v0 = *(const bf16x8*)(Vc + nf * 2048 + vb0);
      bf16x8 v1 = *(const bf16x8*)(Vc + nf * 2048 + vb1);
      acc[nf] = MFMA32(pa0, v0, acc[nf]);
      acc[nf] = MFMA32(pa1, v1, acc[nf]);
    }
    __builtin_amdgcn_s_setprio(0);
  }
  // final l reduction: lane's partial covers q=l31 over its t-half
  lpart += __shfl_xor(lpart, 32);
  float inv = 1.f / lpart;
  float iv[16];
  #pragma unroll
  for (int r = 0; r < 16; r++){
    int qq = (r & 3) + 8 * (r >> 2) + 4 * hi;
    iv[r] = __shfl(inv, qq);
  }
  // epilogue: O /= l, write u [8192][2048]
  unsigned short* ug = u + (size_t)(b * 2048 + q0 + wid * 32) * 2048 + h * 256;
  #pragma unroll
  for (int nf = 0; nf < 8; nf++)
    #pragma unroll
    for (int r = 0; r < 16; r++){
      int qq = (r & 3) + 8 * (r >> 2) + 4 * hi;
      ug[(size_t)qq * 2048 + nf * 32 + l31] = (unsigned short)f2bf(acc[nf][r] * iv[r]);
    }
}

// ---------- output projection: [8192,2048] @ [2048,256] + bias -> fp32 ----------
__global__ __launch_bounds__(256, 2) void k_out(const unsigned short* __restrict__ u,
    const unsigned short* __restrict__ woT, const float* __restrict__ bout, float* __restrict__ out){
  __shared__ unsigned short As[64 * 72];
  __shared__ unsigned short Bs[64 * 72];
  int tid = threadIdx.x;
  int lane = tid & 63, wid = tid >> 6;
  int lr = lane & 15, lg = lane >> 4;
  int wm = (wid >> 1) * 32, wn = (wid & 1) * 32;
  int bn = blockIdx.x, bm = blockIdx.y;
  const unsigned short* Ag = u + (size_t)(bm * 64) * 2048;
  const unsigned short* Bg = woT + (size_t)(bn * 64) * 2048;
  f32x4 acc[2][2] = {};
  for (int kt = 0; kt < 32; kt++){
    ushort8 ra[2], rb[2];
    #pragma unroll
    for (int p = 0; p < 2; p++){
      int idx = p * 256 + tid; int row = idx >> 3, ch = idx & 7;
      ra[p] = *(const ushort8*)(Ag + (size_t)row * 2048 + kt*64 + ch*8);
      rb[p] = *(const ushort8*)(Bg + (size_t)row * 2048 + kt*64 + ch*8);
    }
    __syncthreads();
    #pragma unroll
    for (int p = 0; p < 2; p++){
      int idx = p * 256 + tid; int row = idx >> 3, ch = idx & 7;
      *(ushort8*)(As + row * 72 + ch * 8) = ra[p];
      *(ushort8*)(Bs + row * 72 + ch * 8) = rb[p];
    }
    __syncthreads();
    #pragma unroll
    for (int kf = 0; kf < 2; kf++){
      bf16x8 a0 = *(const bf16x8*)(As + (wm + lr) * 72      + kf*32 + lg*8);
      bf16x8 a1 = *(const bf16x8*)(As + (wm + 16 + lr) * 72 + kf*32 + lg*8);
      bf16x8 b0 = *(const bf16x8*)(Bs + (wn + lr) * 72      + kf*32 + lg*8);
      bf16x8 b1 = *(const bf16x8*)(Bs + (wn + 16 + lr) * 72 + kf*32 + lg*8);
      acc[0][0] = MFMA(a0, b0, acc[0][0]); acc[0][1] = MFMA(a0, b1, acc[0][1]);
      acc[1][0] = MFMA(a1, b0, acc[1][0]); acc[1][1] = MFMA(a1, b1, acc[1][1]);
    }
  }
  #pragma unroll
  for (int mf = 0; mf < 2; mf++)
    #pragma unroll
    for (int nf = 0; nf < 2; nf++){
      int mg = bm*64 + wm + mf*16 + lg*4;
      int ng = bn*64 + wn + nf*16 + lr;
      #pragma unroll
      for (int r2 = 0; r2 < 4; r2++) out[(size_t)(mg + r2) * 256 + ng] = acc[mf][nf][r2] + bout[ng];
    }
}

extern "C" void kernel_launch(void* const* d_in, const int* in_sizes, int n_in,
                              void* d_out, int out_size, void* d_ws, size_t ws_size,
                              hipStream_t stream){
  const float* v    = (const float*)d_in[0];
  const float* WQ   = (const float*)d_in[1];
  const float* WK   = (const float*)d_in[2];
  const float* WV   = (const float*)d_in[3];
  const float* Wout = (const float*)d_in[4];
  const float* bout = (const float*)d_in[5];
  char* ws = (char*)d_ws;
  unsigned short* vb  = (unsigned short*)(ws);                     // v bf16      [8192][256]   4 MB
  unsigned short* wT  = (unsigned short*)(ws + (4u  << 20));       // WQ/WK/WV^T  [3][2048][256] 3 MB (WQ pre-scaled)
  unsigned short* woT = (unsigned short*)(ws + (7u  << 20));       // Wout^T      [256][2048]   1 MB
  unsigned short* qb  = (unsigned short*)(ws + (8u  << 20));       // q  [8192][2048] 32 MB
  unsigned short* kb  = (unsigned short*)(ws + (40u << 20));       // k  [8192][2048] 32 MB
  unsigned short* vTb = (unsigned short*)(ws + (72u << 20));       // vT [b,h,c,s]   32 MB
  unsigned short* ub  = (unsigned short*)(ws + (104u << 20));      // u  [8192][2048] 32 MB
  float* out = (float*)d_out;

  k_prep<<<4096, dim3(32, 8), 0, stream>>>(v, WQ, WK, WV, Wout, vb, wT, woT);
  k_qkv<<<dim3(16, 64, 3), 256, 0, stream>>>(vb, wT, qb, kb, vTb);
  k_attn<<<512, 256, 0, stream>>>(qb, kb, vTb, ub);
  k_out<<<dim3(4, 128), 256, 0, stream>>>(ub, woT, bout, out);
}

// Round 13
// 201.226 us; speedup vs baseline: 1.5541x; 1.0718x over previous
//
#include <hip/hip_runtime.h>
#include <hip/hip_bf16.h>

typedef __bf16 bf16x8 __attribute__((ext_vector_type(8)));
typedef float f32x4 __attribute__((ext_vector_type(4)));
typedef unsigned short ushort8 __attribute__((ext_vector_type(8)));

#define DEVINL static __device__ __forceinline__

DEVINL unsigned f2bf(float f){
  unsigned u = __float_as_uint(f);
  return (u + 0x7fffu + ((u >> 16) & 1u)) >> 16;
}

DEVINL f32x4 MFMA(bf16x8 a, bf16x8 b, f32x4 c){
  return __builtin_amdgcn_mfma_f32_16x16x32_bf16(a, b, c, 0, 0, 0);
}

typedef const __attribute__((address_space(1))) unsigned int* gas_t;
typedef __attribute__((address_space(3))) unsigned int* las_t;
DEVINL void gload_lds16(const void* g, void* l){
  __builtin_amdgcn_global_load_lds((gas_t)g, (las_t)l, 16, 0, 0);
}

// T12 primitives. Verified semantics (gfx950 ISA):
//   sw32(a,b): a=[a.row0, b.row0], b=[a.row1, b.row1]   (row = 32 lanes)
//   sw16(a,b): a=[a.g0, b.g0, a.g2, b.g2], b=[a.g1, b.g1, a.g3, b.g3]  (g = 16 lanes)
DEVINL unsigned cvtpk(float lo, float hi){
  unsigned r; asm("v_cvt_pk_bf16_f32 %0, %1, %2" : "=v"(r) : "v"(lo), "v"(hi)); return r;
}
DEVINL void sw32(unsigned &a, unsigned &b){ asm("v_permlane32_swap_b32 %0, %1" : "+v"(a), "+v"(b)); }
DEVINL void sw16(unsigned &a, unsigned &b){ asm("v_permlane16_swap_b32 %0, %1" : "+v"(a), "+v"(b)); }

// ---------- fused prep: fp32->bf16 pack of v  +  weight transposes (WQ pre-scaled) ----------
__global__ void k_prep(const float* __restrict__ v, const float* __restrict__ WQ,
                       const float* __restrict__ WK, const float* __restrict__ WV,
                       const float* __restrict__ Wout,
                       unsigned short* __restrict__ vb,
                       unsigned short* __restrict__ wT, unsigned short* __restrict__ woT){
  int tid = threadIdx.y * 32 + threadIdx.x;
  int id = blockIdx.x;
  if (id < 2048){
    int i = (id * 256 + tid) * 4;
    float4 x = *(const float4*)(v + i);
    ushort4 o;
    o.x = (unsigned short)f2bf(x.x); o.y = (unsigned short)f2bf(x.y);
    o.z = (unsigned short)f2bf(x.z); o.w = (unsigned short)f2bf(x.w);
    *(ushort4*)(vb + i) = o;
    return;
  }
  __shared__ float t[32][33];
  int id2 = id - 2048;
  const float* s; unsigned short* d; int R, C, tile;
  float scl = 1.0f;
  if (id2 < 1536){
    int z = id2 >> 9; tile = id2 & 511;
    s = (z == 0) ? WQ : ((z == 1) ? WK : WV);
    if (z == 0) scl = 0.25503510f;   // (1/sqrt(32)) * log2(e) folded into WQ
    d = wT + z * 524288; R = 256; C = 2048;
  } else {
    tile = id2 - 1536; s = Wout; d = woT; R = 2048; C = 256;
  }
  int tilesX = C >> 5;
  int c0 = (tile % tilesX) * 32, r0 = (tile / tilesX) * 32;
  int tx = threadIdx.x, ty = threadIdx.y;
  #pragma unroll
  for (int k2 = 0; k2 < 4; k2++) t[ty + 8*k2][tx] = s[(r0 + ty + 8*k2) * C + c0 + tx];
  __syncthreads();
  #pragma unroll
  for (int k2 = 0; k2 < 4; k2++) d[(c0 + ty + 8*k2) * R + r0 + tx] = (unsigned short)f2bf(t[tx][ty + 8*k2] * scl);
}

// ---------- QKV projection: [8192,256] @ [256,2048] -> q,k [8192,2048], val -> vT[b,h,c,s] ----------
// Single-barrier double-buffered K-loop: issue loads(t+1) -> barrier -> compute buf[t&1]
// -> write regs -> buf[(t+1)&1]. Write(t+1) vs last read of that buffer (t-1) separated
// by barrier(t); write(t+1) vs compute(t+1) separated by barrier(t+1).
__global__ __launch_bounds__(256, 2) void k_qkv(const unsigned short* __restrict__ vb,
    const unsigned short* __restrict__ wT,
    unsigned short* __restrict__ qo, unsigned short* __restrict__ ko, unsigned short* __restrict__ vTo){
  __shared__ unsigned short As[2][9216];
  __shared__ unsigned short Bs[2][9216];
  int tid = threadIdx.x;
  int lane = tid & 63, wid = tid >> 6;
  int lr = lane & 15, lg = lane >> 4;
  int wm = (wid >> 1) * 64, wn = (wid & 1) * 64;
  int bn = blockIdx.x, bm = blockIdx.y, z = blockIdx.z;

  const unsigned short* Ag = vb + (bm * 128) * 256;
  const unsigned short* Bg = wT + z * (2048 * 256) + (bn * 128) * 256;

  ushort8 ra[4], rb[4];
  #pragma unroll
  for (int p = 0; p < 4; p++){
    int idx = p * 256 + tid; int row = idx >> 3, ch = idx & 7;
    ra[p] = *(const ushort8*)(Ag + row * 256 + ch * 8);
    rb[p] = *(const ushort8*)(Bg + row * 256 + ch * 8);
  }
  #pragma unroll
  for (int p = 0; p < 4; p++){
    int idx = p * 256 + tid; int row = idx >> 3, ch = idx & 7;
    *(ushort8*)(&As[0][row * 72 + ch * 8]) = ra[p];
    *(ushort8*)(&Bs[0][row * 72 + ch * 8]) = rb[p];
  }

  f32x4 acc[4][4] = {};
  #pragma unroll
  for (int kt = 0; kt < 4; kt++){
    if (kt < 3){
      #pragma unroll
      for (int p = 0; p < 4; p++){
        int idx = p * 256 + tid; int row = idx >> 3, ch = idx & 7;
        ra[p] = *(const ushort8*)(Ag + row * 256 + (kt + 1) * 64 + ch * 8);
        rb[p] = *(const ushort8*)(Bg + row * 256 + (kt + 1) * 64 + ch * 8);
      }
    }
    __syncthreads();
    const unsigned short* Ac = As[kt & 1];
    const unsigned short* Bc = Bs[kt & 1];
    #pragma unroll
    for (int kf = 0; kf < 2; kf++){
      bf16x8 af[4], bfr[4];
      #pragma unroll
      for (int mf = 0; mf < 4; mf++) af[mf]  = *(const bf16x8*)(Ac + (wm + mf*16 + lr) * 72 + kf*32 + lg*8);
      #pragma unroll
      for (int nf = 0; nf < 4; nf++) bfr[nf] = *(const bf16x8*)(Bc + (wn + nf*16 + lr) * 72 + kf*32 + lg*8);
      #pragma unroll
      for (int mf = 0; mf < 4; mf++)
        #pragma unroll
        for (int nf = 0; nf < 4; nf++)
          acc[mf][nf] = MFMA(af[mf], bfr[nf], acc[mf][nf]);
    }
    if (kt < 3){
      #pragma unroll
      for (int p = 0; p < 4; p++){
        int idx = p * 256 + tid; int row = idx >> 3, ch = idx & 7;
        *(ushort8*)(&As[(kt + 1) & 1][row * 72 + ch * 8]) = ra[p];
        *(ushort8*)(&Bs[(kt + 1) & 1][row * 72 + ch * 8]) = rb[p];
      }
    }
  }
  if (z < 2){
    unsigned short* dst = z ? ko : qo;
    #pragma unroll
    for (int mf = 0; mf < 4; mf++)
      #pragma unroll
      for (int nf = 0; nf < 4; nf++){
        int mg = bm*128 + wm + mf*16 + lg*4;
        int ng = bn*128 + wn + nf*16 + lr;
        #pragma unroll
        for (int r2 = 0; r2 < 4; r2++) dst[(mg + r2) * 2048 + ng] = (unsigned short)f2bf(acc[mf][nf][r2]);
      }
  } else {
    #pragma unroll
    for (int mf = 0; mf < 4; mf++)
      #pragma unroll
      for (int nf = 0; nf < 4; nf++){
        int mg = bm*128 + wm + mf*16 + lg*4;
        int ng = bn*128 + wn + nf*16 + lr;
        int bb = mg >> 11, s = mg & 2047, hh = ng >> 8, cc = ng & 255;
        uint2 w;
        w.x = f2bf(acc[mf][nf][0]) | (f2bf(acc[mf][nf][1]) << 16);
        w.y = f2bf(acc[mf][nf][2]) | (f2bf(acc[mf][nf][3]) << 16);
        *(uint2*)(vTo + (size_t)((bb*8 + hh) * 256 + cc) * 2048 + s) = w;
      }
  }
}

// ---------- flash attention: R7 proven kernel (140.7us) + plain exp2 (WQ pre-scaled) ----------
// 4 waves/block; K/V LDS dbuf via gload_lds (pre-swizzled global source, linear dest);
// P in registers (cvt_pk + permlane butterfly); 16x16x32 MFMA (4 indep QK acc chains).
__global__ __launch_bounds__(256, 2) void k_attn(const unsigned short* __restrict__ q,
    const unsigned short* __restrict__ kk, const unsigned short* __restrict__ vT,
    unsigned short* __restrict__ u){
  __shared__ unsigned short Ks[2][8192];
  __shared__ unsigned short Vs[2][8192];
  int tid = threadIdx.x;
  int lane = tid & 63, wid = tid >> 6;
  int lr = lane & 15, lg = lane >> 4;
  // XCD-chunked swizzle: 512 blocks = 8 XCD x 64; each XCD gets 4 contiguous (b,h) pairs
  int g = (blockIdx.x & 7) * 64 + (blockIdx.x >> 3);
  int bh = g >> 4, qt = g & 15;
  int b = bh >> 3, h = bh & 7;
  int q0 = qt * 128;

  const char* kgB = (const char*)(kk + (size_t)b * 2048 * 2048 + h * 256);
  const char* vgB = (const char*)(vT + (size_t)(b * 8 + h) * 256 * 2048);
  const unsigned short* qg = q + (size_t)(b * 2048 + q0 + wid * 32) * 2048 + h * 256;

  // stage one K/V tile (32 KB): 2048 chunks of 16B; waves 0,1 -> K, waves 2,3 -> V
  const char* sp[8];
  bool isK = wid < 2;
  long stepB = isK ? 131072 : 64;   // K: 32 rows * 4096B ; V: 32 t * 2B
  #pragma unroll
  for (int j = 0; j < 8; j++){
    if (isK){
      int c = wid * 512 + j * 64 + lane;
      int row = c >> 5, slot = c & 31;
      sp[j] = kgB + (size_t)row * 4096 + ((slot ^ (row & 7)) * 16);
    } else {
      int c2 = (wid - 2) * 512 + j * 64 + lane;
      int blk = c2 >> 5, ts = (c2 >> 3) & 3, low3 = c2 & 7;
      int crow = blk * 8 + (low3 ^ (ts * 2));
      sp[j] = vgB + (size_t)crow * 4096 + ts * 16;
    }
  }
  int wbase = (wid & 1) * 8192;     // byte offset of this wave's half-tile in LDS
  auto stage = [&](int buf){
    char* db = (char*)(isK ? &Ks[buf][0] : &Vs[buf][0]) + wbase;
    #pragma unroll
    for (int j = 0; j < 8; j++){
      gload_lds16(sp[j], db + j * 1024);
      sp[j] += stepB;
    }
  };

  stage(0);

  // Q -> registers: wave-private 32 rows x 256 (B-operand frags; pre-scaled by SC*log2e)
  bf16x8 qreg[2][8];
  #pragma unroll
  for (int qf = 0; qf < 2; qf++)
    #pragma unroll
    for (int kf = 0; kf < 8; kf++)
      qreg[qf][kf] = *(const bf16x8*)(qg + (size_t)(qf * 16 + lr) * 2048 + kf * 32 + lg * 8);

  f32x4 acc[2][16] = {};
  float lpart[2] = {0.f, 0.f};

  // loop-invariant addressing
  int xA = (lg ^ (lr & 7)) * 16;                                   // K swizzle, kf even
  int vbase = (lr >> 3) * 512 + lg * 128 + (((lr & 7) ^ (lg * 2)) * 16);

  for (int t0 = 0; t0 < 64; t0++){
    int cur = t0 & 1;
    asm volatile("s_waitcnt vmcnt(0)" ::: "memory");   // own stage loads (issued a full tile ago)
    __builtin_amdgcn_s_barrier();                      // all waves' loads visible; prev compute done
    if (t0 + 1 < 64) stage(cur ^ 1);                   // issue-early: lands during this compute
    const char* Kc = (const char*)Ks[cur];
    const char* Vc = (const char*)Vs[cur];

    // QK^T (swapped: A=K so q-rows are lane-local in C cols)
    f32x4 pt[2][2] = {};   // [tf][qf]; row=t, col=q
    const char* ka0 = Kc + lr * 512 + xA;
    const char* ka1 = Kc + lr * 512 + (xA ^ 64);
    __builtin_amdgcn_s_setprio(1);
    #pragma unroll
    for (int kf2 = 0; kf2 < 4; kf2++){
      bf16x8 kE0 = *(const bf16x8*)(ka0 + kf2 * 128);            // tf=0, kf=2*kf2
      bf16x8 kO0 = *(const bf16x8*)(ka1 + kf2 * 128);            // tf=0, kf=2*kf2+1
      bf16x8 kE1 = *(const bf16x8*)(ka0 + 8192 + kf2 * 128);     // tf=1
      bf16x8 kO1 = *(const bf16x8*)(ka1 + 8192 + kf2 * 128);
      pt[0][0] = MFMA(kE0, qreg[0][2*kf2],   pt[0][0]);
      pt[0][1] = MFMA(kE0, qreg[1][2*kf2],   pt[0][1]);
      pt[1][0] = MFMA(kE1, qreg[0][2*kf2],   pt[1][0]);
      pt[1][1] = MFMA(kE1, qreg[1][2*kf2],   pt[1][1]);
      pt[0][0] = MFMA(kO0, qreg[0][2*kf2+1], pt[0][0]);
      pt[0][1] = MFMA(kO0, qreg[1][2*kf2+1], pt[0][1]);
      pt[1][0] = MFMA(kO1, qreg[0][2*kf2+1], pt[1][0]);
      pt[1][1] = MFMA(kO1, qreg[1][2*kf2+1], pt[1][1]);
    }
    __builtin_amdgcn_s_setprio(0);

    // P = exp2(s') directly (scale folded into WQ; constant shift cancels in O/l)
    bf16x8 pa[2];
    #pragma unroll
    for (int qf = 0; qf < 2; qf++){
      float s0 = 0.f, s1 = 0.f;
      #pragma unroll
      for (int tf = 0; tf < 2; tf++)
        #pragma unroll
        for (int r2 = 0; r2 < 4; r2++){
          float e = __builtin_amdgcn_exp2f(pt[tf][qf][r2]);
          pt[tf][qf][r2] = e;
          if (r2 & 1) s1 += e; else s0 += e;
        }
      lpart[qf] += s0 + s1;
      // register butterfly: P^T frag -> PV A-frag (no LDS). dst-first order (verified).
      unsigned A = cvtpk(pt[0][qf][0], pt[0][qf][1]);
      unsigned B = cvtpk(pt[0][qf][2], pt[0][qf][3]);
      unsigned C = cvtpk(pt[1][qf][0], pt[1][qf][1]);
      unsigned D = cvtpk(pt[1][qf][2], pt[1][qf][3]);
      sw32(A, C); sw32(B, D);
      sw16(A, C); sw16(B, D);
      union { unsigned w[4]; bf16x8 v; } cv;
      cv.w[0] = A; cv.w[1] = B; cv.w[2] = C; cv.w[3] = D;
      pa[qf] = cv.v;
    }

    // PV: acc[qrow][c] += P[qrow][t] * V[t][c]  (conflict-free V reads)
    __builtin_amdgcn_s_setprio(1);
    #pragma unroll
    for (int nf = 0; nf < 16; nf++){
      bf16x8 vf = *(const bf16x8*)(Vc + nf * 1024 + vbase);
      acc[0][nf] = MFMA(pa[0], vf, acc[0][nf]);
      acc[1][nf] = MFMA(pa[1], vf, acc[1][nf]);
    }
    __builtin_amdgcn_s_setprio(0);
  }
  // final l reduction (once per kernel)
  #pragma unroll
  for (int qf = 0; qf < 2; qf++){
    lpart[qf] += __shfl_xor(lpart[qf], 16);
    lpart[qf] += __shfl_xor(lpart[qf], 32);
  }
  // epilogue: O /= l, write u [8192][2048]
  #pragma unroll
  for (int mf = 0; mf < 2; mf++){
    float inv = 1.f / lpart[mf];
    float i4[4];
    #pragma unroll
    for (int r2 = 0; r2 < 4; r2++) i4[r2] = __shfl(inv, lg * 4 + r2);
    #pragma unroll
    for (int nf = 0; nf < 16; nf++)
      #pragma unroll
      for (int r2 = 0; r2 < 4; r2++){
        int s = q0 + wid * 32 + mf * 16 + lg * 4 + r2;
        int c = nf * 16 + lr;
        u[(size_t)(b * 2048 + s) * 2048 + h * 256 + c] = (unsigned short)f2bf(acc[mf][nf][r2] * i4[r2]);
      }
  }
}

// ---------- output projection: [8192,2048] @ [2048,256] + bias -> fp32 ----------
// Single-barrier double-buffered K-loop (same discipline as k_qkv).
__global__ __launch_bounds__(256, 2) void k_out(const unsigned short* __restrict__ u,
    const unsigned short* __restrict__ woT, const float* __restrict__ bout, float* __restrict__ out){
  __shared__ unsigned short As[2][4608];
  __shared__ unsigned short Bs[2][4608];
  int tid = threadIdx.x;
  int lane = tid & 63, wid = tid >> 6;
  int lr = lane & 15, lg = lane >> 4;
  int wm = (wid >> 1) * 32, wn = (wid & 1) * 32;
  int bn = blockIdx.x, bm = blockIdx.y;
  const unsigned short* Ag = u + (size_t)(bm * 64) * 2048;
  const unsigned short* Bg = woT + (size_t)(bn * 64) * 2048;

  ushort8 ra[2], rb[2];
  #pragma unroll
  for (int p = 0; p < 2; p++){
    int idx = p * 256 + tid; int row = idx >> 3, ch = idx & 7;
    ra[p] = *(const ushort8*)(Ag + (size_t)row * 2048 + ch * 8);
    rb[p] = *(const ushort8*)(Bg + (size_t)row * 2048 + ch * 8);
  }
  #pragma unroll
  for (int p = 0; p < 2; p++){
    int idx = p * 256 + tid; int row = idx >> 3, ch = idx & 7;
    *(ushort8*)(&As[0][row * 72 + ch * 8]) = ra[p];
    *(ushort8*)(&Bs[0][row * 72 + ch * 8]) = rb[p];
  }

  f32x4 acc[2][2] = {};
  for (int kt = 0; kt < 32; kt++){
    if (kt < 31){
      #pragma unroll
      for (int p = 0; p < 2; p++){
        int idx = p * 256 + tid; int row = idx >> 3, ch = idx & 7;
        ra[p] = *(const ushort8*)(Ag + (size_t)row * 2048 + (kt + 1) * 64 + ch * 8);
        rb[p] = *(const ushort8*)(Bg + (size_t)row * 2048 + (kt + 1) * 64 + ch * 8);
      }
    }
    __syncthreads();
    const unsigned short* Ac = As[kt & 1];
    const unsigned short* Bc = Bs[kt & 1];
    #pragma unroll
    for (int kf = 0; kf < 2; kf++){
      bf16x8 a0 = *(const bf16x8*)(Ac + (wm + lr) * 72      + kf*32 + lg*8);
      bf16x8 a1 = *(const bf16x8*)(Ac + (wm + 16 + lr) * 72 + kf*32 + lg*8);
      bf16x8 b0 = *(const bf16x8*)(Bc + (wn + lr) * 72      + kf*32 + lg*8);
      bf16x8 b1 = *(const bf16x8*)(Bc + (wn + 16 + lr) * 72 + kf*32 + lg*8);
      acc[0][0] = MFMA(a0, b0, acc[0][0]); acc[0][1] = MFMA(a0, b1, acc[0][1]);
      acc[1][0] = MFMA(a1, b0, acc[1][0]); acc[1][1] = MFMA(a1, b1, acc[1][1]);
    }
    if (kt < 31){
      #pragma unroll
      for (int p = 0; p < 2; p++){
        int idx = p * 256 + tid; int row = idx >> 3, ch = idx & 7;
        *(ushort8*)(&As[(kt + 1) & 1][row * 72 + ch * 8]) = ra[p];
        *(ushort8*)(&Bs[(kt + 1) & 1][row * 72 + ch * 8]) = rb[p];
      }
    }
  }
  #pragma unroll
  for (int mf = 0; mf < 2; mf++)
    #pragma unroll
    for (int nf = 0; nf < 2; nf++){
      int mg = bm*64 + wm + mf*16 + lg*4;
      int ng = bn*64 + wn + nf*16 + lr;
      #pragma unroll
      for (int r2 = 0; r2 < 4; r2++) out[(size_t)(mg + r2) * 256 + ng] = acc[mf][nf][r2] + bout[ng];
    }
}

extern "C" void kernel_launch(void* const* d_in, const int* in_sizes, int n_in,
                              void* d_out, int out_size, void* d_ws, size_t ws_size,
                              hipStream_t stream){
  const float* v    = (const float*)d_in[0];
  const float* WQ   = (const float*)d_in[1];
  const float* WK   = (const float*)d_in[2];
  const float* WV   = (const float*)d_in[3];
  const float* Wout = (const float*)d_in[4];
  const float* bout = (const float*)d_in[5];
  char* ws = (char*)d_ws;
  unsigned short* vb  = (unsigned short*)(ws);                     // v bf16      [8192][256]   4 MB
  unsigned short* wT  = (unsigned short*)(ws + (4u  << 20));       // WQ/WK/WV^T  [3][2048][256] 3 MB (WQ pre-scaled)
  unsigned short* woT = (unsigned short*)(ws + (7u  << 20));       // Wout^T      [256][2048]   1 MB
  unsigned short* qb  = (unsigned short*)(ws + (8u  << 20));       // q  [8192][2048] 32 MB
  unsigned short* kb  = (unsigned short*)(ws + (40u << 20));       // k  [8192][2048] 32 MB
  unsigned short* vTb = (unsigned short*)(ws + (72u << 20));       // vT [b,h,c,s]   32 MB
  unsigned short* ub  = (unsigned short*)(ws + (104u << 20));      // u  [8192][2048] 32 MB
  float* out = (float*)d_out;

  k_prep<<<4096, dim3(32, 8), 0, stream>>>(v, WQ, WK, WV, Wout, vb, wT, woT);
  k_qkv<<<dim3(16, 64, 3), 256, 0, stream>>>(vb, wT, qb, kb, vTb);
  k_attn<<<512, 256, 0, stream>>>(qb, kb, vTb, ub);
  k_out<<<dim3(4, 128), 256, 0, stream>>>(ub, woT, bout, out);
}

// Round 14
// 199.455 us; speedup vs baseline: 1.5679x; 1.0089x over previous
//
#include <hip/hip_runtime.h>
#include <hip/hip_bf16.h>

typedef __bf16 bf16x8 __attribute__((ext_vector_type(8)));
typedef float f32x4 __attribute__((ext_vector_type(4)));
typedef unsigned short ushort8 __attribute__((ext_vector_type(8)));

#define DEVINL static __device__ __forceinline__

DEVINL unsigned f2bf(float f){
  unsigned u = __float_as_uint(f);
  return (u + 0x7fffu + ((u >> 16) & 1u)) >> 16;
}

DEVINL f32x4 MFMA(bf16x8 a, bf16x8 b, f32x4 c){
  return __builtin_amdgcn_mfma_f32_16x16x32_bf16(a, b, c, 0, 0, 0);
}

typedef const __attribute__((address_space(1))) unsigned int* gas_t;
typedef __attribute__((address_space(3))) unsigned int* las_t;
DEVINL void gload_lds16(const void* g, void* l){
  __builtin_amdgcn_global_load_lds((gas_t)g, (las_t)l, 16, 0, 0);
}

// T12 primitives. Verified semantics (gfx950 ISA):
//   sw32(a,b): a=[a.row0, b.row0], b=[a.row1, b.row1]   (row = 32 lanes)
//   sw16(a,b): a=[a.g0, b.g0, a.g2, b.g2], b=[a.g1, b.g1, a.g3, b.g3]  (g = 16 lanes)
DEVINL unsigned cvtpk(float lo, float hi){
  unsigned r; asm("v_cvt_pk_bf16_f32 %0, %1, %2" : "=v"(r) : "v"(lo), "v"(hi)); return r;
}
DEVINL void sw32(unsigned &a, unsigned &b){ asm("v_permlane32_swap_b32 %0, %1" : "+v"(a), "+v"(b)); }
DEVINL void sw16(unsigned &a, unsigned &b){ asm("v_permlane16_swap_b32 %0, %1" : "+v"(a), "+v"(b)); }

// ---------- fused prep: fp32->bf16 pack of v  +  weight transposes (WQ pre-scaled) ----------
__global__ void k_prep(const float* __restrict__ v, const float* __restrict__ WQ,
                       const float* __restrict__ WK, const float* __restrict__ WV,
                       const float* __restrict__ Wout,
                       unsigned short* __restrict__ vb,
                       unsigned short* __restrict__ wT, unsigned short* __restrict__ woT){
  int tid = threadIdx.y * 32 + threadIdx.x;
  int id = blockIdx.x;
  if (id < 2048){
    int i = (id * 256 + tid) * 4;
    float4 x = *(const float4*)(v + i);
    ushort4 o;
    o.x = (unsigned short)f2bf(x.x); o.y = (unsigned short)f2bf(x.y);
    o.z = (unsigned short)f2bf(x.z); o.w = (unsigned short)f2bf(x.w);
    *(ushort4*)(vb + i) = o;
    return;
  }
  __shared__ float t[32][33];
  int id2 = id - 2048;
  const float* s; unsigned short* d; int R, C, tile;
  float scl = 1.0f;
  if (id2 < 1536){
    int z = id2 >> 9; tile = id2 & 511;
    s = (z == 0) ? WQ : ((z == 1) ? WK : WV);
    if (z == 0) scl = 0.25503510f;   // (1/sqrt(32)) * log2(e) folded into WQ
    d = wT + z * 524288; R = 256; C = 2048;
  } else {
    tile = id2 - 1536; s = Wout; d = woT; R = 2048; C = 256;
  }
  int tilesX = C >> 5;
  int c0 = (tile % tilesX) * 32, r0 = (tile / tilesX) * 32;
  int tx = threadIdx.x, ty = threadIdx.y;
  #pragma unroll
  for (int k2 = 0; k2 < 4; k2++) t[ty + 8*k2][tx] = s[(r0 + ty + 8*k2) * C + c0 + tx];
  __syncthreads();
  #pragma unroll
  for (int k2 = 0; k2 < 4; k2++) d[(c0 + ty + 8*k2) * R + r0 + tx] = (unsigned short)f2bf(t[tx][ty + 8*k2] * scl);
}

// ---------- QKV projection: [8192,256] @ [256,2048] -> q,k [8192,2048], val -> vT[b,h,c,s] ----------
// Single-barrier double-buffered K-loop; epilogue routes C-tile through LDS scratch so
// ALL global stores are coalesced 16B/lane (z<2: q/k rows; z=2: vT [cc][s] rows).
__global__ __launch_bounds__(256, 2) void k_qkv(const unsigned short* __restrict__ vb,
    const unsigned short* __restrict__ wT,
    unsigned short* __restrict__ qo, unsigned short* __restrict__ ko, unsigned short* __restrict__ vTo){
  __shared__ unsigned short As[2][9216];
  __shared__ unsigned short Bs[2][9216];
  int tid = threadIdx.x;
  int lane = tid & 63, wid = tid >> 6;
  int lr = lane & 15, lg = lane >> 4;
  int wm = (wid >> 1) * 64, wn = (wid & 1) * 64;
  int bn = blockIdx.x, bm = blockIdx.y, z = blockIdx.z;

  const unsigned short* Ag = vb + (bm * 128) * 256;
  const unsigned short* Bg = wT + z * (2048 * 256) + (bn * 128) * 256;

  ushort8 ra[4], rb[4];
  #pragma unroll
  for (int p = 0; p < 4; p++){
    int idx = p * 256 + tid; int row = idx >> 3, ch = idx & 7;
    ra[p] = *(const ushort8*)(Ag + row * 256 + ch * 8);
    rb[p] = *(const ushort8*)(Bg + row * 256 + ch * 8);
  }
  #pragma unroll
  for (int p = 0; p < 4; p++){
    int idx = p * 256 + tid; int row = idx >> 3, ch = idx & 7;
    *(ushort8*)(&As[0][row * 72 + ch * 8]) = ra[p];
    *(ushort8*)(&Bs[0][row * 72 + ch * 8]) = rb[p];
  }

  f32x4 acc[4][4] = {};
  #pragma unroll
  for (int kt = 0; kt < 4; kt++){
    if (kt < 3){
      #pragma unroll
      for (int p = 0; p < 4; p++){
        int idx = p * 256 + tid; int row = idx >> 3, ch = idx & 7;
        ra[p] = *(const ushort8*)(Ag + row * 256 + (kt + 1) * 64 + ch * 8);
        rb[p] = *(const ushort8*)(Bg + row * 256 + (kt + 1) * 64 + ch * 8);
      }
    }
    __syncthreads();
    const unsigned short* Ac = As[kt & 1];
    const unsigned short* Bc = Bs[kt & 1];
    #pragma unroll
    for (int kf = 0; kf < 2; kf++){
      bf16x8 af[4], bfr[4];
      #pragma unroll
      for (int mf = 0; mf < 4; mf++) af[mf]  = *(const bf16x8*)(Ac + (wm + mf*16 + lr) * 72 + kf*32 + lg*8);
      #pragma unroll
      for (int nf = 0; nf < 4; nf++) bfr[nf] = *(const bf16x8*)(Bc + (wn + nf*16 + lr) * 72 + kf*32 + lg*8);
      #pragma unroll
      for (int mf = 0; mf < 4; mf++)
        #pragma unroll
        for (int nf = 0; nf < 4; nf++)
          acc[mf][nf] = MFMA(af[mf], bfr[nf], acc[mf][nf]);
    }
    if (kt < 3){
      #pragma unroll
      for (int p = 0; p < 4; p++){
        int idx = p * 256 + tid; int row = idx >> 3, ch = idx & 7;
        *(ushort8*)(&As[(kt + 1) & 1][row * 72 + ch * 8]) = ra[p];
        *(ushort8*)(&Bs[(kt + 1) & 1][row * 72 + ch * 8]) = rb[p];
      }
    }
  }
  // ---- epilogue via LDS scratch: [128][136] shorts (row stride 272B, 16B-aligned) ----
  __syncthreads();                       // all MFMA LDS reads done; reuse As as scratch
  unsigned short* T = &As[0][0];         // 128*136 = 17408 shorts <= 18432 available
  if (z < 2){
    // store C[mg][ng] row-major
    #pragma unroll
    for (int mf = 0; mf < 4; mf++)
      #pragma unroll
      for (int nf = 0; nf < 4; nf++){
        int mg0 = wm + mf*16 + lg*4;
        int ng  = wn + nf*16 + lr;
        #pragma unroll
        for (int r2 = 0; r2 < 4; r2++) T[(mg0 + r2) * 136 + ng] = (unsigned short)f2bf(acc[mf][nf][r2]);
      }
    __syncthreads();
    unsigned short* dst = z ? (unsigned short*)ko : (unsigned short*)qo;
    int rr = tid >> 3, cs = (tid & 7) * 8;
    #pragma unroll
    for (int rg = 0; rg < 4; rg++)
      #pragma unroll
      for (int chh = 0; chh < 2; chh++){
        int row = rg * 32 + rr, col = chh * 64 + cs;
        ushort8 w = *(const ushort8*)(T + row * 136 + col);
        *(ushort8*)(dst + (size_t)(bm*128 + row) * 2048 + bn*128 + col) = w;
      }
  } else {
    // store C^T as [ng(cc)][mg(s)] rows (s-contiguous pairs via uint)
    #pragma unroll
    for (int mf = 0; mf < 4; mf++)
      #pragma unroll
      for (int nf = 0; nf < 4; nf++){
        int mg0 = wm + mf*16 + lg*4;
        int ng  = wn + nf*16 + lr;
        *(unsigned*)&T[ng * 136 + mg0]     = f2bf(acc[mf][nf][0]) | (f2bf(acc[mf][nf][1]) << 16);
        *(unsigned*)&T[ng * 136 + mg0 + 2] = f2bf(acc[mf][nf][2]) | (f2bf(acc[mf][nf][3]) << 16);
      }
    __syncthreads();
    int bb = bm >> 4, hh = bn >> 1;
    int ccb = (bn & 1) * 128, sb = (bm & 15) * 128;
    int rr = tid >> 3, cs = (tid & 7) * 8;
    #pragma unroll
    for (int rg = 0; rg < 4; rg++)
      #pragma unroll
      for (int chh = 0; chh < 2; chh++){
        int row = rg * 32 + rr, col = chh * 64 + cs;   // row = cc_local, col = s_local
        ushort8 w = *(const ushort8*)(T + row * 136 + col);
        *(ushort8*)(vTo + (size_t)((bb*8 + hh) * 256 + ccb + row) * 2048 + sb + col) = w;
      }
  }
}

// ---------- flash attention: R7 proven kernel + plain exp2 (WQ pre-scaled) ----------
// 4 waves/block; K/V LDS dbuf via gload_lds (pre-swizzled global source, linear dest);
// P in registers (cvt_pk + permlane butterfly); 16x16x32 MFMA (4 indep QK acc chains).
__global__ __launch_bounds__(256, 2) void k_attn(const unsigned short* __restrict__ q,
    const unsigned short* __restrict__ kk, const unsigned short* __restrict__ vT,
    unsigned short* __restrict__ u){
  __shared__ unsigned short Ks[2][8192];
  __shared__ unsigned short Vs[2][8192];
  int tid = threadIdx.x;
  int lane = tid & 63, wid = tid >> 6;
  int lr = lane & 15, lg = lane >> 4;
  // XCD-chunked swizzle: 512 blocks = 8 XCD x 64; each XCD gets 4 contiguous (b,h) pairs
  int g = (blockIdx.x & 7) * 64 + (blockIdx.x >> 3);
  int bh = g >> 4, qt = g & 15;
  int b = bh >> 3, h = bh & 7;
  int q0 = qt * 128;

  const char* kgB = (const char*)(kk + (size_t)b * 2048 * 2048 + h * 256);
  const char* vgB = (const char*)(vT + (size_t)(b * 8 + h) * 256 * 2048);
  const unsigned short* qg = q + (size_t)(b * 2048 + q0 + wid * 32) * 2048 + h * 256;

  // stage one K/V tile (32 KB): 2048 chunks of 16B; waves 0,1 -> K, waves 2,3 -> V
  const char* sp[8];
  bool isK = wid < 2;
  long stepB = isK ? 131072 : 64;   // K: 32 rows * 4096B ; V: 32 t * 2B
  #pragma unroll
  for (int j = 0; j < 8; j++){
    if (isK){
      int c = wid * 512 + j * 64 + lane;
      int row = c >> 5, slot = c & 31;
      sp[j] = kgB + (size_t)row * 4096 + ((slot ^ (row & 7)) * 16);
    } else {
      int c2 = (wid - 2) * 512 + j * 64 + lane;
      int blk = c2 >> 5, ts = (c2 >> 3) & 3, low3 = c2 & 7;
      int crow = blk * 8 + (low3 ^ (ts * 2));
      sp[j] = vgB + (size_t)crow * 4096 + ts * 16;
    }
  }
  int wbase = (wid & 1) * 8192;     // byte offset of this wave's half-tile in LDS
  auto stage = [&](int buf){
    char* db = (char*)(isK ? &Ks[buf][0] : &Vs[buf][0]) + wbase;
    #pragma unroll
    for (int j = 0; j < 8; j++){
      gload_lds16(sp[j], db + j * 1024);
      sp[j] += stepB;
    }
  };

  stage(0);

  // Q -> registers: wave-private 32 rows x 256 (B-operand frags; pre-scaled by SC*log2e)
  bf16x8 qreg[2][8];
  #pragma unroll
  for (int qf = 0; qf < 2; qf++)
    #pragma unroll
    for (int kf = 0; kf < 8; kf++)
      qreg[qf][kf] = *(const bf16x8*)(qg + (size_t)(qf * 16 + lr) * 2048 + kf * 32 + lg * 8);

  f32x4 acc[2][16] = {};
  float lpart[2] = {0.f, 0.f};

  // loop-invariant addressing
  int xA = (lg ^ (lr & 7)) * 16;                                   // K swizzle, kf even
  int vbase = (lr >> 3) * 512 + lg * 128 + (((lr & 7) ^ (lg * 2)) * 16);

  for (int t0 = 0; t0 < 64; t0++){
    int cur = t0 & 1;
    asm volatile("s_waitcnt vmcnt(0)" ::: "memory");   // own stage loads (issued a full tile ago)
    __builtin_amdgcn_s_barrier();                      // all waves' loads visible; prev compute done
    if (t0 + 1 < 64) stage(cur ^ 1);                   // issue-early: lands during this compute
    const char* Kc = (const char*)Ks[cur];
    const char* Vc = (const char*)Vs[cur];

    // QK^T (swapped: A=K so q-rows are lane-local in C cols)
    f32x4 pt[2][2] = {};   // [tf][qf]; row=t, col=q
    const char* ka0 = Kc + lr * 512 + xA;
    const char* ka1 = Kc + lr * 512 + (xA ^ 64);
    __builtin_amdgcn_s_setprio(1);
    #pragma unroll
    for (int kf2 = 0; kf2 < 4; kf2++){
      bf16x8 kE0 = *(const bf16x8*)(ka0 + kf2 * 128);            // tf=0, kf=2*kf2
      bf16x8 kO0 = *(const bf16x8*)(ka1 + kf2 * 128);            // tf=0, kf=2*kf2+1
      bf16x8 kE1 = *(const bf16x8*)(ka0 + 8192 + kf2 * 128);     // tf=1
      bf16x8 kO1 = *(const bf16x8*)(ka1 + 8192 + kf2 * 128);
      pt[0][0] = MFMA(kE0, qreg[0][2*kf2],   pt[0][0]);
      pt[0][1] = MFMA(kE0, qreg[1][2*kf2],   pt[0][1]);
      pt[1][0] = MFMA(kE1, qreg[0][2*kf2],   pt[1][0]);
      pt[1][1] = MFMA(kE1, qreg[1][2*kf2],   pt[1][1]);
      pt[0][0] = MFMA(kO0, qreg[0][2*kf2+1], pt[0][0]);
      pt[0][1] = MFMA(kO0, qreg[1][2*kf2+1], pt[0][1]);
      pt[1][0] = MFMA(kO1, qreg[0][2*kf2+1], pt[1][0]);
      pt[1][1] = MFMA(kO1, qreg[1][2*kf2+1], pt[1][1]);
    }
    __builtin_amdgcn_s_setprio(0);

    // P = exp2(s') directly (scale folded into WQ; constant shift cancels in O/l)
    bf16x8 pa[2];
    #pragma unroll
    for (int qf = 0; qf < 2; qf++){
      float s0 = 0.f, s1 = 0.f;
      #pragma unroll
      for (int tf = 0; tf < 2; tf++)
        #pragma unroll
        for (int r2 = 0; r2 < 4; r2++){
          float e = __builtin_amdgcn_exp2f(pt[tf][qf][r2]);
          pt[tf][qf][r2] = e;
          if (r2 & 1) s1 += e; else s0 += e;
        }
      lpart[qf] += s0 + s1;
      // register butterfly: P^T frag -> PV A-frag (no LDS). dst-first order (verified).
      unsigned A = cvtpk(pt[0][qf][0], pt[0][qf][1]);
      unsigned B = cvtpk(pt[0][qf][2], pt[0][qf][3]);
      unsigned C = cvtpk(pt[1][qf][0], pt[1][qf][1]);
      unsigned D = cvtpk(pt[1][qf][2], pt[1][qf][3]);
      sw32(A, C); sw32(B, D);
      sw16(A, C); sw16(B, D);
      union { unsigned w[4]; bf16x8 v; } cv;
      cv.w[0] = A; cv.w[1] = B; cv.w[2] = C; cv.w[3] = D;
      pa[qf] = cv.v;
    }

    // PV: acc[qrow][c] += P[qrow][t] * V[t][c]  (conflict-free V reads)
    __builtin_amdgcn_s_setprio(1);
    #pragma unroll
    for (int nf = 0; nf < 16; nf++){
      bf16x8 vf = *(const bf16x8*)(Vc + nf * 1024 + vbase);
      acc[0][nf] = MFMA(pa[0], vf, acc[0][nf]);
      acc[1][nf] = MFMA(pa[1], vf, acc[1][nf]);
    }
    __builtin_amdgcn_s_setprio(0);
  }
  // final l reduction (once per kernel)
  #pragma unroll
  for (int qf = 0; qf < 2; qf++){
    lpart[qf] += __shfl_xor(lpart[qf], 16);
    lpart[qf] += __shfl_xor(lpart[qf], 32);
  }
  // epilogue: O /= l, write u [8192][2048]
  #pragma unroll
  for (int mf = 0; mf < 2; mf++){
    float inv = 1.f / lpart[mf];
    float i4[4];
    #pragma unroll
    for (int r2 = 0; r2 < 4; r2++) i4[r2] = __shfl(inv, lg * 4 + r2);
    #pragma unroll
    for (int nf = 0; nf < 16; nf++)
      #pragma unroll
      for (int r2 = 0; r2 < 4; r2++){
        int s = q0 + wid * 32 + mf * 16 + lg * 4 + r2;
        int c = nf * 16 + lr;
        u[(size_t)(b * 2048 + s) * 2048 + h * 256 + c] = (unsigned short)f2bf(acc[mf][nf][r2] * i4[r2]);
      }
  }
}

// ---------- output projection: [8192,2048] @ [2048,256] + bias -> fp32 ----------
// Single-barrier double-buffered K-loop (same discipline as k_qkv).
__global__ __launch_bounds__(256, 2) void k_out(const unsigned short* __restrict__ u,
    const unsigned short* __restrict__ woT, const float* __restrict__ bout, float* __restrict__ out){
  __shared__ unsigned short As[2][4608];
  __shared__ unsigned short Bs[2][4608];
  int tid = threadIdx.x;
  int lane = tid & 63, wid = tid >> 6;
  int lr = lane & 15, lg = lane >> 4;
  int wm = (wid >> 1) * 32, wn = (wid & 1) * 32;
  int bn = blockIdx.x, bm = blockIdx.y;
  const unsigned short* Ag = u + (size_t)(bm * 64) * 2048;
  const unsigned short* Bg = woT + (size_t)(bn * 64) * 2048;

  ushort8 ra[2], rb[2];
  #pragma unroll
  for (int p = 0; p < 2; p++){
    int idx = p * 256 + tid; int row = idx >> 3, ch = idx & 7;
    ra[p] = *(const ushort8*)(Ag + (size_t)row * 2048 + ch * 8);
    rb[p] = *(const ushort8*)(Bg + (size_t)row * 2048 + ch * 8);
  }
  #pragma unroll
  for (int p = 0; p < 2; p++){
    int idx = p * 256 + tid; int row = idx >> 3, ch = idx & 7;
    *(ushort8*)(&As[0][row * 72 + ch * 8]) = ra[p];
    *(ushort8*)(&Bs[0][row * 72 + ch * 8]) = rb[p];
  }

  f32x4 acc[2][2] = {};
  for (int kt = 0; kt < 32; kt++){
    if (kt < 31){
      #pragma unroll
      for (int p = 0; p < 2; p++){
        int idx = p * 256 + tid; int row = idx >> 3, ch = idx & 7;
        ra[p] = *(const ushort8*)(Ag + (size_t)row * 2048 + (kt + 1) * 64 + ch * 8);
        rb[p] = *(const ushort8*)(Bg + (size_t)row * 2048 + (kt + 1) * 64 + ch * 8);
      }
    }
    __syncthreads();
    const unsigned short* Ac = As[kt & 1];
    const unsigned short* Bc = Bs[kt & 1];
    #pragma unroll
    for (int kf = 0; kf < 2; kf++){
      bf16x8 a0 = *(const bf16x8*)(Ac + (wm + lr) * 72      + kf*32 + lg*8);
      bf16x8 a1 = *(const bf16x8*)(Ac + (wm + 16 + lr) * 72 + kf*32 + lg*8);
      bf16x8 b0 = *(const bf16x8*)(Bc + (wn + lr) * 72      + kf*32 + lg*8);
      bf16x8 b1 = *(const bf16x8*)(Bc + (wn + 16 + lr) * 72 + kf*32 + lg*8);
      acc[0][0] = MFMA(a0, b0, acc[0][0]); acc[0][1] = MFMA(a0, b1, acc[0][1]);
      acc[1][0] = MFMA(a1, b0, acc[1][0]); acc[1][1] = MFMA(a1, b1, acc[1][1]);
    }
    if (kt < 31){
      #pragma unroll
      for (int p = 0; p < 2; p++){
        int idx = p * 256 + tid; int row = idx >> 3, ch = idx & 7;
        *(ushort8*)(&As[(kt + 1) & 1][row * 72 + ch * 8]) = ra[p];
        *(ushort8*)(&Bs[(kt + 1) & 1][row * 72 + ch * 8]) = rb[p];
      }
    }
  }
  #pragma unroll
  for (int mf = 0; mf < 2; mf++)
    #pragma unroll
    for (int nf = 0; nf < 2; nf++){
      int mg = bm*64 + wm + mf*16 + lg*4;
      int ng = bn*64 + wn + nf*16 + lr;
      #pragma unroll
      for (int r2 = 0; r2 < 4; r2++) out[(size_t)(mg + r2) * 256 + ng] = acc[mf][nf][r2] + bout[ng];
    }
}

extern "C" void kernel_launch(void* const* d_in, const int* in_sizes, int n_in,
                              void* d_out, int out_size, void* d_ws, size_t ws_size,
                              hipStream_t stream){
  const float* v    = (const float*)d_in[0];
  const float* WQ   = (const float*)d_in[1];
  const float* WK   = (const float*)d_in[2];
  const float* WV   = (const float*)d_in[3];
  const float* Wout = (const float*)d_in[4];
  const float* bout = (const float*)d_in[5];
  char* ws = (char*)d_ws;
  unsigned short* vb  = (unsigned short*)(ws);                     // v bf16      [8192][256]   4 MB
  unsigned short* wT  = (unsigned short*)(ws + (4u  << 20));       // WQ/WK/WV^T  [3][2048][256] 3 MB (WQ pre-scaled)
  unsigned short* woT = (unsigned short*)(ws + (7u  << 20));       // Wout^T      [256][2048]   1 MB
  unsigned short* qb  = (unsigned short*)(ws + (8u  << 20));       // q  [8192][2048] 32 MB
  unsigned short* kb  = (unsigned short*)(ws + (40u << 20));       // k  [8192][2048] 32 MB
  unsigned short* vTb = (unsigned short*)(ws + (72u << 20));       // vT [b,h,c,s]   32 MB
  unsigned short* ub  = (unsigned short*)(ws + (104u << 20));      // u  [8192][2048] 32 MB
  float* out = (float*)d_out;

  k_prep<<<4096, dim3(32, 8), 0, stream>>>(v, WQ, WK, WV, Wout, vb, wT, woT);
  k_qkv<<<dim3(16, 64, 3), 256, 0, stream>>>(vb, wT, qb, kb, vTb);
  k_attn<<<512, 256, 0, stream>>>(qb, kb, vTb, ub);
  k_out<<<dim3(4, 128), 256, 0, stream>>>(ub, woT, bout, out);
}

// Round 16
// 199.097 us; speedup vs baseline: 1.5707x; 1.0018x over previous
//
#include <hip/hip_runtime.h>
#include <hip/hip_bf16.h>

typedef __bf16 bf16x8 __attribute__((ext_vector_type(8)));
typedef float f32x4 __attribute__((ext_vector_type(4)));
typedef unsigned short ushort8 __attribute__((ext_vector_type(8)));

#define DEVINL static __device__ __forceinline__

DEVINL unsigned f2bf(float f){
  unsigned u = __float_as_uint(f);
  return (u + 0x7fffu + ((u >> 16) & 1u)) >> 16;
}

DEVINL f32x4 MFMA(bf16x8 a, bf16x8 b, f32x4 c){
  return __builtin_amdgcn_mfma_f32_16x16x32_bf16(a, b, c, 0, 0, 0);
}

typedef const __attribute__((address_space(1))) unsigned int* gas_t;
typedef __attribute__((address_space(3))) unsigned int* las_t;
DEVINL void gload_lds16(const void* g, void* l){
  __builtin_amdgcn_global_load_lds((gas_t)g, (las_t)l, 16, 0, 0);
}

// T12 primitives. Verified semantics (gfx950 ISA):
//   sw32(a,b): a=[a.row0, b.row0], b=[a.row1, b.row1]   (row = 32 lanes)
//   sw16(a,b): a=[a.g0, b.g0, a.g2, b.g2], b=[a.g1, b.g1, a.g3, b.g3]  (g = 16 lanes)
DEVINL unsigned cvtpk(float lo, float hi){
  unsigned r; asm("v_cvt_pk_bf16_f32 %0, %1, %2" : "=v"(r) : "v"(lo), "v"(hi)); return r;
}
DEVINL void sw32(unsigned &a, unsigned &b){ asm("v_permlane32_swap_b32 %0, %1" : "+v"(a), "+v"(b)); }
DEVINL void sw16(unsigned &a, unsigned &b){ asm("v_permlane16_swap_b32 %0, %1" : "+v"(a), "+v"(b)); }

// ---------- fused prep: fp32->bf16 pack of v  +  weight transposes (WQ pre-scaled) ----------
__global__ void k_prep(const float* __restrict__ v, const float* __restrict__ WQ,
                       const float* __restrict__ WK, const float* __restrict__ WV,
                       const float* __restrict__ Wout,
                       unsigned short* __restrict__ vb,
                       unsigned short* __restrict__ wT, unsigned short* __restrict__ woT){
  int tid = threadIdx.y * 32 + threadIdx.x;
  int id = blockIdx.x;
  if (id < 2048){
    int i = (id * 256 + tid) * 4;
    float4 x = *(const float4*)(v + i);
    ushort4 o;
    o.x = (unsigned short)f2bf(x.x); o.y = (unsigned short)f2bf(x.y);
    o.z = (unsigned short)f2bf(x.z); o.w = (unsigned short)f2bf(x.w);
    *(ushort4*)(vb + i) = o;
    return;
  }
  __shared__ float t[32][33];
  int id2 = id - 2048;
  const float* s; unsigned short* d; int R, C, tile;
  float scl = 1.0f;
  if (id2 < 1536){
    int z = id2 >> 9; tile = id2 & 511;
    s = (z == 0) ? WQ : ((z == 1) ? WK : WV);
    if (z == 0) scl = 0.25503510f;   // (1/sqrt(32)) * log2(e) folded into WQ
    d = wT + z * 524288; R = 256; C = 2048;
  } else {
    tile = id2 - 1536; s = Wout; d = woT; R = 2048; C = 256;
  }
  int tilesX = C >> 5;
  int c0 = (tile % tilesX) * 32, r0 = (tile / tilesX) * 32;
  int tx = threadIdx.x, ty = threadIdx.y;
  #pragma unroll
  for (int k2 = 0; k2 < 4; k2++) t[ty + 8*k2][tx] = s[(r0 + ty + 8*k2) * C + c0 + tx];
  __syncthreads();
  #pragma unroll
  for (int k2 = 0; k2 < 4; k2++) d[(c0 + ty + 8*k2) * R + r0 + tx] = (unsigned short)f2bf(t[tx][ty + 8*k2] * scl);
}

// ---------- QKV projection: [8192,256] @ [256,2048] -> q,k [8192,2048], val -> vT[b,h,c,s] ----------
// Single-barrier double-buffered K-loop; epilogue routes C-tile through LDS scratch so
// ALL global stores are coalesced 16B/lane (z<2: q/k rows; z=2: vT [cc][s] rows).
__global__ __launch_bounds__(256, 2) void k_qkv(const unsigned short* __restrict__ vb,
    const unsigned short* __restrict__ wT,
    unsigned short* __restrict__ qo, unsigned short* __restrict__ ko, unsigned short* __restrict__ vTo){
  __shared__ unsigned short As[2][9216];
  __shared__ unsigned short Bs[2][9216];
  int tid = threadIdx.x;
  int lane = tid & 63, wid = tid >> 6;
  int lr = lane & 15, lg = lane >> 4;
  int wm = (wid >> 1) * 64, wn = (wid & 1) * 64;
  int bn = blockIdx.x, bm = blockIdx.y, z = blockIdx.z;

  const unsigned short* Ag = vb + (bm * 128) * 256;
  const unsigned short* Bg = wT + z * (2048 * 256) + (bn * 128) * 256;

  ushort8 ra[4], rb[4];
  #pragma unroll
  for (int p = 0; p < 4; p++){
    int idx = p * 256 + tid; int row = idx >> 3, ch = idx & 7;
    ra[p] = *(const ushort8*)(Ag + row * 256 + ch * 8);
    rb[p] = *(const ushort8*)(Bg + row * 256 + ch * 8);
  }
  #pragma unroll
  for (int p = 0; p < 4; p++){
    int idx = p * 256 + tid; int row = idx >> 3, ch = idx & 7;
    *(ushort8*)(&As[0][row * 72 + ch * 8]) = ra[p];
    *(ushort8*)(&Bs[0][row * 72 + ch * 8]) = rb[p];
  }

  f32x4 acc[4][4] = {};
  #pragma unroll
  for (int kt = 0; kt < 4; kt++){
    if (kt < 3){
      #pragma unroll
      for (int p = 0; p < 4; p++){
        int idx = p * 256 + tid; int row = idx >> 3, ch = idx & 7;
        ra[p] = *(const ushort8*)(Ag + row * 256 + (kt + 1) * 64 + ch * 8);
        rb[p] = *(const ushort8*)(Bg + row * 256 + (kt + 1) * 64 + ch * 8);
      }
    }
    __syncthreads();
    const unsigned short* Ac = As[kt & 1];
    const unsigned short* Bc = Bs[kt & 1];
    #pragma unroll
    for (int kf = 0; kf < 2; kf++){
      bf16x8 af[4], bfr[4];
      #pragma unroll
      for (int mf = 0; mf < 4; mf++) af[mf]  = *(const bf16x8*)(Ac + (wm + mf*16 + lr) * 72 + kf*32 + lg*8);
      #pragma unroll
      for (int nf = 0; nf < 4; nf++) bfr[nf] = *(const bf16x8*)(Bc + (wn + nf*16 + lr) * 72 + kf*32 + lg*8);
      #pragma unroll
      for (int mf = 0; mf < 4; mf++)
        #pragma unroll
        for (int nf = 0; nf < 4; nf++)
          acc[mf][nf] = MFMA(af[mf], bfr[nf], acc[mf][nf]);
    }
    if (kt < 3){
      #pragma unroll
      for (int p = 0; p < 4; p++){
        int idx = p * 256 + tid; int row = idx >> 3, ch = idx & 7;
        *(ushort8*)(&As[(kt + 1) & 1][row * 72 + ch * 8]) = ra[p];
        *(ushort8*)(&Bs[(kt + 1) & 1][row * 72 + ch * 8]) = rb[p];
      }
    }
  }
  // ---- epilogue via LDS scratch: [128][136] shorts (row stride 272B, 16B-aligned) ----
  __syncthreads();                       // all MFMA LDS reads done; reuse As as scratch
  unsigned short* T = &As[0][0];         // 128*136 = 17408 shorts <= 18432 available
  if (z < 2){
    // store C[mg][ng] row-major
    #pragma unroll
    for (int mf = 0; mf < 4; mf++)
      #pragma unroll
      for (int nf = 0; nf < 4; nf++){
        int mg0 = wm + mf*16 + lg*4;
        int ng  = wn + nf*16 + lr;
        #pragma unroll
        for (int r2 = 0; r2 < 4; r2++) T[(mg0 + r2) * 136 + ng] = (unsigned short)f2bf(acc[mf][nf][r2]);
      }
    __syncthreads();
    unsigned short* dst = z ? (unsigned short*)ko : (unsigned short*)qo;
    int rr = tid >> 3, cs = (tid & 7) * 8;
    #pragma unroll
    for (int rg = 0; rg < 4; rg++)
      #pragma unroll
      for (int chh = 0; chh < 2; chh++){
        int row = rg * 32 + rr, col = chh * 64 + cs;
        ushort8 w = *(const ushort8*)(T + row * 136 + col);
        *(ushort8*)(dst + (size_t)(bm*128 + row) * 2048 + bn*128 + col) = w;
      }
  } else {
    // store C^T as [ng(cc)][mg(s)] rows (s-contiguous pairs via uint)
    #pragma unroll
    for (int mf = 0; mf < 4; mf++)
      #pragma unroll
      for (int nf = 0; nf < 4; nf++){
        int mg0 = wm + mf*16 + lg*4;
        int ng  = wn + nf*16 + lr;
        *(unsigned*)&T[ng * 136 + mg0]     = f2bf(acc[mf][nf][0]) | (f2bf(acc[mf][nf][1]) << 16);
        *(unsigned*)&T[ng * 136 + mg0 + 2] = f2bf(acc[mf][nf][2]) | (f2bf(acc[mf][nf][3]) << 16);
      }
    __syncthreads();
    int bb = bm >> 4, hh = bn >> 1;
    int ccb = (bn & 1) * 128, sb = (bm & 15) * 128;
    int rr = tid >> 3, cs = (tid & 7) * 8;
    #pragma unroll
    for (int rg = 0; rg < 4; rg++)
      #pragma unroll
      for (int chh = 0; chh < 2; chh++){
        int row = rg * 32 + rr, col = chh * 64 + cs;   // row = cc_local, col = s_local
        ushort8 w = *(const ushort8*)(T + row * 136 + col);
        *(ushort8*)(vTo + (size_t)((bb*8 + hh) * 256 + ccb + row) * 2048 + sb + col) = w;
      }
  }
}

// ---------- flash attention: R7 proven kernel + plain exp2 (WQ pre-scaled) ----------
// 4 waves/block; K/V LDS dbuf via gload_lds (pre-swizzled global source, linear dest);
// P in registers (cvt_pk + permlane butterfly); 16x16x32 MFMA (4 indep QK acc chains).
__global__ __launch_bounds__(256, 2) void k_attn(const unsigned short* __restrict__ q,
    const unsigned short* __restrict__ kk, const unsigned short* __restrict__ vT,
    unsigned short* __restrict__ u){
  __shared__ unsigned short Ks[2][8192];
  __shared__ unsigned short Vs[2][8192];
  int tid = threadIdx.x;
  int lane = tid & 63, wid = tid >> 6;
  int lr = lane & 15, lg = lane >> 4;
  // XCD-chunked swizzle: 512 blocks = 8 XCD x 64; each XCD gets 4 contiguous (b,h) pairs
  int g = (blockIdx.x & 7) * 64 + (blockIdx.x >> 3);
  int bh = g >> 4, qt = g & 15;
  int b = bh >> 3, h = bh & 7;
  int q0 = qt * 128;

  const char* kgB = (const char*)(kk + (size_t)b * 2048 * 2048 + h * 256);
  const char* vgB = (const char*)(vT + (size_t)(b * 8 + h) * 256 * 2048);
  const unsigned short* qg = q + (size_t)(b * 2048 + q0 + wid * 32) * 2048 + h * 256;

  // stage one K/V tile (32 KB): 2048 chunks of 16B; waves 0,1 -> K, waves 2,3 -> V
  const char* sp[8];
  bool isK = wid < 2;
  long stepB = isK ? 131072 : 64;   // K: 32 rows * 4096B ; V: 32 t * 2B
  #pragma unroll
  for (int j = 0; j < 8; j++){
    if (isK){
      int c = wid * 512 + j * 64 + lane;
      int row = c >> 5, slot = c & 31;
      sp[j] = kgB + (size_t)row * 4096 + ((slot ^ (row & 7)) * 16);
    } else {
      int c2 = (wid - 2) * 512 + j * 64 + lane;
      int blk = c2 >> 5, ts = (c2 >> 3) & 3, low3 = c2 & 7;
      int crow = blk * 8 + (low3 ^ (ts * 2));
      sp[j] = vgB + (size_t)crow * 4096 + ts * 16;
    }
  }
  int wbase = (wid & 1) * 8192;     // byte offset of this wave's half-tile in LDS
  auto stage = [&](int buf){
    char* db = (char*)(isK ? &Ks[buf][0] : &Vs[buf][0]) + wbase;
    #pragma unroll
    for (int j = 0; j < 8; j++){
      gload_lds16(sp[j], db + j * 1024);
      sp[j] += stepB;
    }
  };

  stage(0);

  // Q -> registers: wave-private 32 rows x 256 (B-operand frags; pre-scaled by SC*log2e)
  bf16x8 qreg[2][8];
  #pragma unroll
  for (int qf = 0; qf < 2; qf++)
    #pragma unroll
    for (int kf = 0; kf < 8; kf++)
      qreg[qf][kf] = *(const bf16x8*)(qg + (size_t)(qf * 16 + lr) * 2048 + kf * 32 + lg * 8);

  f32x4 acc[2][16] = {};
  float lpart[2] = {0.f, 0.f};

  // loop-invariant addressing
  int xA = (lg ^ (lr & 7)) * 16;                                   // K swizzle, kf even
  int vbase = (lr >> 3) * 512 + lg * 128 + (((lr & 7) ^ (lg * 2)) * 16);

  for (int t0 = 0; t0 < 64; t0++){
    int cur = t0 & 1;
    asm volatile("s_waitcnt vmcnt(0)" ::: "memory");   // own stage loads (issued a full tile ago)
    __builtin_amdgcn_s_barrier();                      // all waves' loads visible; prev compute done
    if (t0 + 1 < 64) stage(cur ^ 1);                   // issue-early: lands during this compute
    const char* Kc = (const char*)Ks[cur];
    const char* Vc = (const char*)Vs[cur];

    // QK^T (swapped: A=K so q-rows are lane-local in C cols)
    f32x4 pt[2][2] = {};   // [tf][qf]; row=t, col=q
    const char* ka0 = Kc + lr * 512 + xA;
    const char* ka1 = Kc + lr * 512 + (xA ^ 64);
    __builtin_amdgcn_s_setprio(1);
    #pragma unroll
    for (int kf2 = 0; kf2 < 4; kf2++){
      bf16x8 kE0 = *(const bf16x8*)(ka0 + kf2 * 128);            // tf=0, kf=2*kf2
      bf16x8 kO0 = *(const bf16x8*)(ka1 + kf2 * 128);            // tf=0, kf=2*kf2+1
      bf16x8 kE1 = *(const bf16x8*)(ka0 + 8192 + kf2 * 128);     // tf=1
      bf16x8 kO1 = *(const bf16x8*)(ka1 + 8192 + kf2 * 128);
      pt[0][0] = MFMA(kE0, qreg[0][2*kf2],   pt[0][0]);
      pt[0][1] = MFMA(kE0, qreg[1][2*kf2],   pt[0][1]);
      pt[1][0] = MFMA(kE1, qreg[0][2*kf2],   pt[1][0]);
      pt[1][1] = MFMA(kE1, qreg[1][2*kf2],   pt[1][1]);
      pt[0][0] = MFMA(kO0, qreg[0][2*kf2+1], pt[0][0]);
      pt[0][1] = MFMA(kO0, qreg[1][2*kf2+1], pt[0][1]);
      pt[1][0] = MFMA(kO1, qreg[0][2*kf2+1], pt[1][0]);
      pt[1][1] = MFMA(kO1, qreg[1][2*kf2+1], pt[1][1]);
    }
    __builtin_amdgcn_s_setprio(0);

    // P = exp2(s') directly (scale folded into WQ; constant shift cancels in O/l)
    bf16x8 pa[2];
    #pragma unroll
    for (int qf = 0; qf < 2; qf++){
      float s0 = 0.f, s1 = 0.f;
      #pragma unroll
      for (int tf = 0; tf < 2; tf++)
        #pragma unroll
        for (int r2 = 0; r2 < 4; r2++){
          float e = __builtin_amdgcn_exp2f(pt[tf][qf][r2]);
          pt[tf][qf][r2] = e;
          if (r2 & 1) s1 += e; else s0 += e;
        }
      lpart[qf] += s0 + s1;
      // register butterfly: P^T frag -> PV A-frag (no LDS). dst-first order (verified).
      unsigned A = cvtpk(pt[0][qf][0], pt[0][qf][1]);
      unsigned B = cvtpk(pt[0][qf][2], pt[0][qf][3]);
      unsigned C = cvtpk(pt[1][qf][0], pt[1][qf][1]);
      unsigned D = cvtpk(pt[1][qf][2], pt[1][qf][3]);
      sw32(A, C); sw32(B, D);
      sw16(A, C); sw16(B, D);
      union { unsigned w[4]; bf16x8 v; } cv;
      cv.w[0] = A; cv.w[1] = B; cv.w[2] = C; cv.w[3] = D;
      pa[qf] = cv.v;
    }

    // PV: acc[qrow][c] += P[qrow][t] * V[t][c]  (conflict-free V reads)
    __builtin_amdgcn_s_setprio(1);
    #pragma unroll
    for (int nf = 0; nf < 16; nf++){
      bf16x8 vf = *(const bf16x8*)(Vc + nf * 1024 + vbase);
      acc[0][nf] = MFMA(pa[0], vf, acc[0][nf]);
      acc[1][nf] = MFMA(pa[1], vf, acc[1][nf]);
    }
    __builtin_amdgcn_s_setprio(0);
  }
  // final l reduction (once per kernel)
  #pragma unroll
  for (int qf = 0; qf < 2; qf++){
    lpart[qf] += __shfl_xor(lpart[qf], 16);
    lpart[qf] += __shfl_xor(lpart[qf], 32);
  }
  // epilogue: O /= l, write u [8192][2048]
  #pragma unroll
  for (int mf = 0; mf < 2; mf++){
    float inv = 1.f / lpart[mf];
    float i4[4];
    #pragma unroll
    for (int r2 = 0; r2 < 4; r2++) i4[r2] = __shfl(inv, lg * 4 + r2);
    #pragma unroll
    for (int nf = 0; nf < 16; nf++)
      #pragma unroll
      for (int r2 = 0; r2 < 4; r2++){
        int s = q0 + wid * 32 + mf * 16 + lg * 4 + r2;
        int c = nf * 16 + lr;
        u[(size_t)(b * 2048 + s) * 2048 + h * 256 + c] = (unsigned short)f2bf(acc[mf][nf][r2] * i4[r2]);
      }
  }
}

// ---------- output projection: [8192,2048] @ [2048,256] + bias -> fp32 ----------
// Single-barrier double-buffered K-loop (same discipline as k_qkv).
__global__ __launch_bounds__(256, 2) void k_out(const unsigned short* __restrict__ u,
    const unsigned short* __restrict__ woT, const float* __restrict__ bout, float* __restrict__ out){
  __shared__ unsigned short As[2][4608];
  __shared__ unsigned short Bs[2][4608];
  int tid = threadIdx.x;
  int lane = tid & 63, wid = tid >> 6;
  int lr = lane & 15, lg = lane >> 4;
  int wm = (wid >> 1) * 32, wn = (wid & 1) * 32;
  int bn = blockIdx.x, bm = blockIdx.y;
  const unsigned short* Ag = u + (size_t)(bm * 64) * 2048;
  const unsigned short* Bg = woT + (size_t)(bn * 64) * 2048;

  ushort8 ra[2], rb[2];
  #pragma unroll
  for (int p = 0; p < 2; p++){
    int idx = p * 256 + tid; int row = idx >> 3, ch = idx & 7;
    ra[p] = *(const ushort8*)(Ag + (size_t)row * 2048 + ch * 8);
    rb[p] = *(const ushort8*)(Bg + (size_t)row * 2048 + ch * 8);
  }
  #pragma unroll
  for (int p = 0; p < 2; p++){
    int idx = p * 256 + tid; int row = idx >> 3, ch = idx & 7;
    *(ushort8*)(&As[0][row * 72 + ch * 8]) = ra[p];
    *(ushort8*)(&Bs[0][row * 72 + ch * 8]) = rb[p];
  }

  f32x4 acc[2][2] = {};
  for (int kt = 0; kt < 32; kt++){
    if (kt < 31){
      #pragma unroll
      for (int p = 0; p < 2; p++){
        int idx = p * 256 + tid; int row = idx >> 3, ch = idx & 7;
        ra[p] = *(const ushort8*)(Ag + (size_t)row * 2048 + (kt + 1) * 64 + ch * 8);
        rb[p] = *(const ushort8*)(Bg + (size_t)row * 2048 + (kt + 1) * 64 + ch * 8);
      }
    }
    __syncthreads();
    const unsigned short* Ac = As[kt & 1];
    const unsigned short* Bc = Bs[kt & 1];
    #pragma unroll
    for (int kf = 0; kf < 2; kf++){
      bf16x8 a0 = *(const bf16x8*)(Ac + (wm + lr) * 72      + kf*32 + lg*8);
      bf16x8 a1 = *(const bf16x8*)(Ac + (wm + 16 + lr) * 72 + kf*32 + lg*8);
      bf16x8 b0 = *(const bf16x8*)(Bc + (wn + lr) * 72      + kf*32 + lg*8);
      bf16x8 b1 = *(const bf16x8*)(Bc + (wn + 16 + lr) * 72 + kf*32 + lg*8);
      acc[0][0] = MFMA(a0, b0, acc[0][0]); acc[0][1] = MFMA(a0, b1, acc[0][1]);
      acc[1][0] = MFMA(a1, b0, acc[1][0]); acc[1][1] = MFMA(a1, b1, acc[1][1]);
    }
    if (kt < 31){
      #pragma unroll
      for (int p = 0; p < 2; p++){
        int idx = p * 256 + tid; int row = idx >> 3, ch = idx & 7;
        *(ushort8*)(&As[(kt + 1) & 1][row * 72 + ch * 8]) = ra[p];
        *(ushort8*)(&Bs[(kt + 1) & 1][row * 72 + ch * 8]) = rb[p];
      }
    }
  }
  #pragma unroll
  for (int mf = 0; mf < 2; mf++)
    #pragma unroll
    for (int nf = 0; nf < 2; nf++){
      int mg = bm*64 + wm + mf*16 + lg*4;
      int ng = bn*64 + wn + nf*16 + lr;
      #pragma unroll
      for (int r2 = 0; r2 < 4; r2++) out[(size_t)(mg + r2) * 256 + ng] = acc[mf][nf][r2] + bout[ng];
    }
}

extern "C" void kernel_launch(void* const* d_in, const int* in_sizes, int n_in,
                              void* d_out, int out_size, void* d_ws, size_t ws_size,
                              hipStream_t stream){
  const float* v    = (const float*)d_in[0];
  const float* WQ   = (const float*)d_in[1];
  const float* WK   = (const float*)d_in[2];
  const float* WV   = (const float*)d_in[3];
  const float* Wout = (const float*)d_in[4];
  const float* bout = (const float*)d_in[5];
  char* ws = (char*)d_ws;
  unsigned short* vb  = (unsigned short*)(ws);                     // v bf16      [8192][256]   4 MB
  unsigned short* wT  = (unsigned short*)(ws + (4u  << 20));       // WQ/WK/WV^T  [3][2048][256] 3 MB (WQ pre-scaled)
  unsigned short* woT = (unsigned short*)(ws + (7u  << 20));       // Wout^T      [256][2048]   1 MB
  unsigned short* qb  = (unsigned short*)(ws + (8u  << 20));       // q  [8192][2048] 32 MB
  unsigned short* kb  = (unsigned short*)(ws + (40u << 20));       // k  [8192][2048] 32 MB
  unsigned short* vTb = (unsigned short*)(ws + (72u << 20));       // vT [b,h,c,s]   32 MB
  unsigned short* ub  = (unsigned short*)(ws + (104u << 20));      // u  [8192][2048] 32 MB
  float* out = (float*)d_out;

  k_prep<<<4096, dim3(32, 8), 0, stream>>>(v, WQ, WK, WV, Wout, vb, wT, woT);
  k_qkv<<<dim3(16, 64, 3), 256, 0, stream>>>(vb, wT, qb, kb, vTb);
  k_attn<<<512, 256, 0, stream>>>(qb, kb, vTb, ub);
  k_out<<<dim3(4, 128), 256, 0, stream>>>(ub, woT, bout, out);
}